// Round 8
// baseline (53470.831 us; speedup 1.0000x reference)
//
#include <hip/hip_runtime.h>
#include <hip/hip_fp16.h>

// LSTM_54537494725306: 2-layer LSTM, T=2048, D=512, H=2048, OUT=64, fp32 in/out.
// R10 = R9 structure (temporal split, LDS-resident Whh, no spill - verified:
// VGPR 88, FETCH 214MB/sweep, 40.2ms) with the per-step sync chain shortened.
// R9 post-mortem: step = 9.4us, compute ~0.5us (VALUBusy 12%), HBM ~0.1% --
// the two-level barrier's 3 serialized agent-scope hops + exposed G/h load
// latency dominate.
// Changes (sweep kernel only):
//   1. Monotonic-counter barrier: one atomicAdd per WG per step; pollers wait
//      for count >= 256*(t+1). Removes the level-2 atomic hop and the release-
//      store hop. No reset (counter grows to 256*T < 2^31). Correct by
//      induction: a WG's (t+2)-th arrival requires passing wait(t), so
//      count = 256(t+1) implies all WGs arrived t+1 times.
//   2. Split-phase: arrive right after the h-store drains, prefetch G[t+1]
//      into registers while the grid converges, then wait. G latency (~0.9us)
//      leaves the critical path.
// Phases: GEMM1 (x@Wih1^T) -> sweepA (Whh1 in 128KiB LDS/CU) -> GEMM2
// (h1@Wih2^T) -> sweepB (Whh2 in LDS) -> GEMMY (h2@Wlin^T + b).
// Math identical to R9 (fp16 weights -> f32 cvt -> f32 fmaf chains).

#define T_STEPS 2048
#define DIM_D   512
#define DIM_H   2048
#define DIM_H4  8192
#define DIM_OUT 64
#define NTHR    512

#define N_WIH1 (4 * DIM_H * DIM_D)   //  4,194,304
#define N_WHH1 (4 * DIM_H * DIM_H)   // 16,777,216
#define N_WIH2 (4 * DIM_H * DIM_H)
#define N_WHH2 (4 * DIM_H * DIM_H)
#define N_WLIN (DIM_OUT * DIM_H)     //    131,072
#define WS_WEIGHT_OFF 65536

__device__ __forceinline__ float sigf(float x)   { return 1.0f / (1.0f + __expf(-x)); }
__device__ __forceinline__ float tanh_f(float x) { return 1.0f - 2.0f / (__expf(2.0f * x) + 1.0f); }

__device__ __forceinline__ float wave_reduce(float v) {
#pragma unroll
    for (int off = 32; off > 0; off >>= 1) v += __shfl_xor(v, off, 64);
    return v;
}

struct F8 { float4 a, b; };

__device__ __forceinline__ F8 load8(const float* __restrict__ p, int e) {
    F8 r;
    const float4* q = (const float4*)(p + e);
    r.a = q[0]; r.b = q[1];
    return r;
}

__device__ __forceinline__ F8 cvt8(uint4 u) {
    float2 f0 = __half22float2(*(__half2*)&u.x);
    float2 f1 = __half22float2(*(__half2*)&u.y);
    float2 f2 = __half22float2(*(__half2*)&u.z);
    float2 f3 = __half22float2(*(__half2*)&u.w);
    F8 r;
    r.a = make_float4(f0.x, f0.y, f1.x, f1.y);
    r.b = make_float4(f2.x, f2.y, f3.x, f3.y);
    return r;
}

__device__ __forceinline__ F8 load8(const __half* __restrict__ p, int e) {
    uint4 u = *(const uint4*)(p + e);
    return cvt8(u);
}

__device__ __forceinline__ float dot8(const F8& v, const F8& w, float acc) {
    acc = fmaf(v.a.x, w.a.x, acc); acc = fmaf(v.a.y, w.a.y, acc);
    acc = fmaf(v.a.z, w.a.z, acc); acc = fmaf(v.a.w, w.a.w, acc);
    acc = fmaf(v.b.x, w.b.x, acc); acc = fmaf(v.b.y, w.b.y, acc);
    acc = fmaf(v.b.z, w.b.z, acc); acc = fmaf(v.b.w, w.b.w, acc);
    return acc;
}

// 4-row dot over K elements (streaming fallback path only).
template<int K, typename WT>
__device__ __forceinline__ void dot4(const float* __restrict__ v,
                                     const WT* __restrict__ w0, const WT* __restrict__ w1,
                                     const WT* __restrict__ w2, const WT* __restrict__ w3,
                                     int lane, float& a0, float& a1, float& a2, float& a3) {
#pragma unroll
    for (int i = 0; i < K / 512; ++i) {
        const int e = (lane + 64 * i) * 8;
        const F8 vv = load8(v, e);
        a0 = dot8(vv, load8(w0, e), a0);
        a1 = dot8(vv, load8(w1, e), a1);
        a2 = dot8(vv, load8(w2, e), a2);
        a3 = dot8(vv, load8(w3, e), a3);
    }
}

// Two-level sense-free barrier over NGRP*32 workgroups (fallback kernels only).
template<int NGRP>
__device__ __forceinline__ void grid_barrier(int* bar, int wg, int g) {
    __syncthreads();
    if (threadIdx.x == 0) {
        const int grp = wg >> 5;
        int a = __hip_atomic_fetch_add(&bar[grp * 32], 1, __ATOMIC_ACQ_REL, __HIP_MEMORY_SCOPE_AGENT);
        if (a == 31) {
            int r = __hip_atomic_fetch_add(&bar[NGRP * 32], 1, __ATOMIC_ACQ_REL, __HIP_MEMORY_SCOPE_AGENT);
            if (r == NGRP - 1) {
#pragma unroll
                for (int i = 0; i < NGRP; ++i)
                    __hip_atomic_store(&bar[i * 32], 0, __ATOMIC_RELAXED, __HIP_MEMORY_SCOPE_AGENT);
                __hip_atomic_store(&bar[NGRP * 32], 0, __ATOMIC_RELAXED, __HIP_MEMORY_SCOPE_AGENT);
                __hip_atomic_store(&bar[NGRP * 32 + 32], g + 1, __ATOMIC_RELEASE, __HIP_MEMORY_SCOPE_AGENT);
            }
        }
        while (__hip_atomic_load(&bar[NGRP * 32 + 32], __ATOMIC_RELAXED, __HIP_MEMORY_SCOPE_AGENT) <= g) {
            __builtin_amdgcn_s_sleep(2);
        }
        __builtin_amdgcn_fence(__ATOMIC_ACQUIRE, "agent");
    }
    __syncthreads();
}

__global__ void lstm_init(int* bar, float* h1buf, float* h2buf) {
    int i = threadIdx.x + blockIdx.x * blockDim.x;
    if (i < 1024) bar[i] = 0;
    if (i < 2 * DIM_H) { h1buf[i] = 0.0f; h2buf[i] = 0.0f; }
}

// fp32 -> fp16 (RNE), 4 elements/thread.
__global__ void convert_f16(const float* __restrict__ src, __half* __restrict__ dst, int n4) {
    int i = threadIdx.x + blockIdx.x * blockDim.x;
    if (i < n4) {
        float4 f = ((const float4*)src)[i];
        __half2 h01 = __floats2half2_rn(f.x, f.y);
        __half2 h23 = __floats2half2_rn(f.z, f.w);
        uint2 o;
        o.x = *(unsigned int*)&h01;
        o.y = *(unsigned int*)&h23;
        ((uint2*)dst)[i] = o;
    }
}

// ---------------------------------------------------------------------------
// GEMM: C[M][N] = A[M][K](fp32) * B[N][K](fp16)^T  (+ bias[n] if hasBias).
// 64x64 tile, 256 threads, 4x4 micro-tile/thread, K-chunks of 32.
// ---------------------------------------------------------------------------
#define GT_M 64
#define GT_N 64
#define GT_K 32

__global__ __launch_bounds__(256) void gemm_xwT(
    const float* __restrict__ A, const __half* __restrict__ B,
    const float* __restrict__ bias, float* __restrict__ C,
    int M, int N, int K, int hasBias)
{
    __shared__ float  As[GT_K][GT_M + 4];   // [32][68] fp32, 8.5 KB
    __shared__ ushort Bs[GT_K][GT_N + 8];   // [32][72] fp16 bits, 4.5 KB

    const int t  = threadIdx.x;
    const int tx = t & 15, ty = t >> 4;
    const int n0 = blockIdx.x * GT_N;
    const int m0 = blockIdx.y * GT_M;

    float acc[4][4];
#pragma unroll
    for (int i = 0; i < 4; ++i)
#pragma unroll
        for (int j = 0; j < 4; ++j) acc[i][j] = 0.f;

    for (int kc = 0; kc < K; kc += GT_K) {
#pragma unroll
        for (int s = 0; s < 2; ++s) {
            const int i  = t + s * 256;
            const int r  = i >> 3;
            const int c4 = (i & 7) * 4;
            const float4 av = *(const float4*)(A + (size_t)(m0 + r) * K + kc + c4);
            As[c4 + 0][r] = av.x; As[c4 + 1][r] = av.y;
            As[c4 + 2][r] = av.z; As[c4 + 3][r] = av.w;
            const uint2 bv = *(const uint2*)(B + (size_t)(n0 + r) * K + kc + c4);
            Bs[c4 + 0][r] = (ushort)(bv.x & 0xffffu);
            Bs[c4 + 1][r] = (ushort)(bv.x >> 16);
            Bs[c4 + 2][r] = (ushort)(bv.y & 0xffffu);
            Bs[c4 + 3][r] = (ushort)(bv.y >> 16);
        }
        __syncthreads();
#pragma unroll
        for (int kk = 0; kk < GT_K; ++kk) {
            const float4 a4 = *(const float4*)&As[kk][ty * 4];
            const uint2  bu = *(const uint2*)&Bs[kk][tx * 4];
            const float2 b01 = __half22float2(*(const __half2*)&bu.x);
            const float2 b23 = __half22float2(*(const __half2*)&bu.y);
            const float a0 = a4.x, a1 = a4.y, a2 = a4.z, a3 = a4.w;
            const float b0 = b01.x, b1 = b01.y, b2 = b23.x, b3 = b23.y;
            acc[0][0] = fmaf(a0, b0, acc[0][0]); acc[0][1] = fmaf(a0, b1, acc[0][1]);
            acc[0][2] = fmaf(a0, b2, acc[0][2]); acc[0][3] = fmaf(a0, b3, acc[0][3]);
            acc[1][0] = fmaf(a1, b0, acc[1][0]); acc[1][1] = fmaf(a1, b1, acc[1][1]);
            acc[1][2] = fmaf(a1, b2, acc[1][2]); acc[1][3] = fmaf(a1, b3, acc[1][3]);
            acc[2][0] = fmaf(a2, b0, acc[2][0]); acc[2][1] = fmaf(a2, b1, acc[2][1]);
            acc[2][2] = fmaf(a2, b2, acc[2][2]); acc[2][3] = fmaf(a2, b3, acc[2][3]);
            acc[3][0] = fmaf(a3, b0, acc[3][0]); acc[3][1] = fmaf(a3, b1, acc[3][1]);
            acc[3][2] = fmaf(a3, b2, acc[3][2]); acc[3][3] = fmaf(a3, b3, acc[3][3]);
        }
        __syncthreads();
    }

    float4 bv = make_float4(0.f, 0.f, 0.f, 0.f);
    if (hasBias) {
        const int n = n0 + tx * 4;
        bv = make_float4(bias[n], bias[n + 1], bias[n + 2], bias[n + 3]);
    }
#pragma unroll
    for (int i = 0; i < 4; ++i) {
        const int m = m0 + ty * 4 + i;
        float4 v = make_float4(acc[i][0] + bv.x, acc[i][1] + bv.y,
                               acc[i][2] + bv.z, acc[i][3] + bv.w);
        *(float4*)(C + (size_t)m * N + n0 + tx * 4) = v;
    }
}

// ---------------------------------------------------------------------------
// Sequential sweep with monotonic-counter split-phase barrier.
// 256 WGs x 512 thr (8 waves), 1 wave per unit; Whh rows in 128 KiB LDS/CU.
// Per step: dots vs LDS + wave_reduce + gate math; arrive -> prefetch G[t+1]
// -> wait(count >= 256*(t+1)) -> next step.
// ---------------------------------------------------------------------------
__global__ __launch_bounds__(NTHR, 2) void lstm_sweep(
    const float* __restrict__ G,     // [T][4H] x-part pre-activations
    const __half* __restrict__ Whh,  // [4H][H] fp16
    const float* __restrict__ bi, const float* __restrict__ bh,
    float* __restrict__ h_all,       // [T][H]
    int* bar)                        // monotonic counter at bar[0]
{
    const int wg   = blockIdx.x;
    const int wave = threadIdx.x >> 6;
    const int lane = threadIdx.x & 63;
    const int unit = wg * 8 + wave;

    __shared__ uint4 ldsW[8][4][DIM_H / 8];   // 131072 B

#pragma unroll
    for (int g = 0; g < 4; ++g) {
        const uint4* q = (const uint4*)(Whh + (size_t)(g * DIM_H + unit) * DIM_H);
#pragma unroll
        for (int j = 0; j < 4; ++j)
            ldsW[wave][g][lane + 64 * j] = q[lane + 64 * j];
    }
    const float b0 = bi[0 * DIM_H + unit] + bh[0 * DIM_H + unit];
    const float b1 = bi[1 * DIM_H + unit] + bh[1 * DIM_H + unit];
    const float b2 = bi[2 * DIM_H + unit] + bh[2 * DIM_H + unit];
    const float b3 = bi[3 * DIM_H + unit] + bh[3 * DIM_H + unit];
    __syncthreads();

    float c = 0.0f;

    // G[0] preloaded (same-address across lanes -> broadcast).
    float g0 = G[0 * DIM_H + unit];
    float g1 = G[1 * DIM_H + unit];
    float g2 = G[2 * DIM_H + unit];
    float g3 = G[3 * DIM_H + unit];

    for (int t = 0; t < T_STEPS; ++t) {
        float a0 = 0.f, a1 = 0.f, a2 = 0.f, a3 = 0.f;
        if (t > 0) {
            const float* hp = h_all + (size_t)(t - 1) * DIM_H;
#pragma unroll
            for (int j = 0; j < 4; ++j) {
                const F8 hv = load8(hp, (lane + 64 * j) * 8);
                a0 = dot8(hv, cvt8(ldsW[wave][0][lane + 64 * j]), a0);
                a1 = dot8(hv, cvt8(ldsW[wave][1][lane + 64 * j]), a1);
                a2 = dot8(hv, cvt8(ldsW[wave][2][lane + 64 * j]), a2);
                a3 = dot8(hv, cvt8(ldsW[wave][3][lane + 64 * j]), a3);
            }
            a0 = wave_reduce(a0); a1 = wave_reduce(a1);
            a2 = wave_reduce(a2); a3 = wave_reduce(a3);
        }

        const float gi = sigf  (a0 + g0 + b0);
        const float gf = sigf  (a1 + g1 + b1);
        const float gg = tanh_f(a2 + g2 + b2);
        const float go = sigf  (a3 + g3 + b3);
        c = fmaf(gf, c, gi * gg);
        const float hv = go * tanh_f(c);
        if (lane == 0) h_all[(size_t)t * DIM_H + unit] = hv;

        // ---- arrive (after h store drains via syncthreads' vmcnt wait) ----
        __syncthreads();
        if (threadIdx.x == 0)
            __hip_atomic_fetch_add(&bar[0], 1, __ATOMIC_ACQ_REL, __HIP_MEMORY_SCOPE_AGENT);

        // ---- prefetch next-step G while the grid converges ----
        const size_t nb = (size_t)((t + 1 < T_STEPS) ? t + 1 : t) * DIM_H4;
        const float n0 = G[nb + 0 * DIM_H + unit];
        const float n1 = G[nb + 1 * DIM_H + unit];
        const float n2 = G[nb + 2 * DIM_H + unit];
        const float n3 = G[nb + 3 * DIM_H + unit];

        // ---- wait: all 256 WGs arrived for step t ----
        if (threadIdx.x == 0) {
            const int tgt = 256 * (t + 1);
            while (__hip_atomic_load(&bar[0], __ATOMIC_RELAXED, __HIP_MEMORY_SCOPE_AGENT) < tgt) {
                __builtin_amdgcn_s_sleep(2);
            }
            __builtin_amdgcn_fence(__ATOMIC_ACQUIRE, "agent");
        }
        __syncthreads();

        g0 = n0; g1 = n1; g2 = n2; g3 = n3;
    }
}

// ---------------------------------------------------------------------------
// Fallback: R2-style weight streaming, 256 WGs x 8 waves (proven correct).
// ---------------------------------------------------------------------------
template<typename WT>
__global__ __launch_bounds__(NTHR, 2) void lstm_stream(
    const float* __restrict__ x,
    const WT* __restrict__ Wih1, const WT* __restrict__ Whh1,
    const float* __restrict__ bih1, const float* __restrict__ bhh1,
    const WT* __restrict__ Wih2, const WT* __restrict__ Whh2,
    const float* __restrict__ bih2, const float* __restrict__ bhh2,
    const WT* __restrict__ Wlin, const float* __restrict__ blin,
    float* __restrict__ out,
    int* bar, float* h1buf, float* h2buf)
{
    const int wg   = blockIdx.x;
    const int wave = threadIdx.x >> 6;
    const int lane = threadIdx.x & 63;
    const int unit = wg * 8 + wave;

    const int r0 = unit, r1 = DIM_H + unit, r2 = 2 * DIM_H + unit, r3 = 3 * DIM_H + unit;
    const float b1_0 = bih1[r0] + bhh1[r0];
    const float b1_1 = bih1[r1] + bhh1[r1];
    const float b1_2 = bih1[r2] + bhh1[r2];
    const float b1_3 = bih1[r3] + bhh1[r3];
    const float b2_0 = bih2[r0] + bhh2[r0];
    const float b2_1 = bih2[r1] + bhh2[r1];
    const float b2_2 = bih2[r2] + bhh2[r2];
    const float b2_3 = bih2[r3] + bhh2[r3];

    const WT* wi1_0 = Wih1 + (size_t)r0 * DIM_D;
    const WT* wi1_1 = Wih1 + (size_t)r1 * DIM_D;
    const WT* wi1_2 = Wih1 + (size_t)r2 * DIM_D;
    const WT* wi1_3 = Wih1 + (size_t)r3 * DIM_D;
    const WT* wh1_0 = Whh1 + (size_t)r0 * DIM_H;
    const WT* wh1_1 = Whh1 + (size_t)r1 * DIM_H;
    const WT* wh1_2 = Whh1 + (size_t)r2 * DIM_H;
    const WT* wh1_3 = Whh1 + (size_t)r3 * DIM_H;
    const WT* wi2_0 = Wih2 + (size_t)r0 * DIM_H;
    const WT* wi2_1 = Wih2 + (size_t)r1 * DIM_H;
    const WT* wi2_2 = Wih2 + (size_t)r2 * DIM_H;
    const WT* wi2_3 = Wih2 + (size_t)r3 * DIM_H;
    const WT* wh2_0 = Whh2 + (size_t)r0 * DIM_H;
    const WT* wh2_1 = Whh2 + (size_t)r1 * DIM_H;
    const WT* wh2_2 = Whh2 + (size_t)r2 * DIM_H;
    const WT* wh2_3 = Whh2 + (size_t)r3 * DIM_H;

    const bool  do_y = (wg < DIM_OUT) && (wave == 0);
    const float by   = (wg < DIM_OUT) ? blin[wg] : 0.0f;
    const WT*   wy   = Wlin + (size_t)(wg < DIM_OUT ? wg : 0) * DIM_H;

    float c1 = 0.0f, c2 = 0.0f;

    for (int p = 0; p < T_STEPS + 2; ++p) {
        const float* h1_prev  = h1buf + (size_t)((p + 1) & 1) * DIM_H;
        float*       h1_cur   = h1buf + (size_t)(p & 1) * DIM_H;
        const float* h2_prev2 = h2buf + (size_t)(p & 1) * DIM_H;
        float*       h2_cur   = h2buf + (size_t)((p + 1) & 1) * DIM_H;

        if (p < T_STEPS) {
            float a0 = 0.f, a1 = 0.f, a2 = 0.f, a3 = 0.f;
            dot4<DIM_D>(x + (size_t)p * DIM_D, wi1_0, wi1_1, wi1_2, wi1_3, lane, a0, a1, a2, a3);
            dot4<DIM_H>(h1_prev, wh1_0, wh1_1, wh1_2, wh1_3, lane, a0, a1, a2, a3);
            a0 = wave_reduce(a0); a1 = wave_reduce(a1);
            a2 = wave_reduce(a2); a3 = wave_reduce(a3);
            const float gi = sigf(a0 + b1_0);
            const float gf = sigf(a1 + b1_1);
            const float gg = tanh_f(a2 + b1_2);
            const float go = sigf(a3 + b1_3);
            c1 = fmaf(gf, c1, gi * gg);
            if (lane == 0) h1_cur[unit] = go * tanh_f(c1);
        }

        if (p >= 1 && p <= T_STEPS) {
            float a0 = 0.f, a1 = 0.f, a2 = 0.f, a3 = 0.f;
            dot4<DIM_H>(h1_prev,  wi2_0, wi2_1, wi2_2, wi2_3, lane, a0, a1, a2, a3);
            dot4<DIM_H>(h2_prev2, wh2_0, wh2_1, wh2_2, wh2_3, lane, a0, a1, a2, a3);
            a0 = wave_reduce(a0); a1 = wave_reduce(a1);
            a2 = wave_reduce(a2); a3 = wave_reduce(a3);
            const float gi = sigf(a0 + b2_0);
            const float gf = sigf(a1 + b2_1);
            const float gg = tanh_f(a2 + b2_2);
            const float go = sigf(a3 + b2_3);
            c2 = fmaf(gf, c2, gi * gg);
            if (lane == 0) h2_cur[unit] = go * tanh_f(c2);
        }

        if (do_y && p >= 2) {
            float a = 0.f;
#pragma unroll
            for (int i = 0; i < DIM_H / 512; ++i) {
                const int e = (lane + 64 * i) * 8;
                a = dot8(load8(h2_prev2, e), load8(wy, e), a);
            }
            a = wave_reduce(a);
            if (lane == 0) out[(size_t)(p - 2) * DIM_OUT + wg] = a + by;
        }

        grid_barrier<8>(bar, wg, p);
    }
}

extern "C" void kernel_launch(void* const* d_in, const int* in_sizes, int n_in,
                              void* d_out, int out_size, void* d_ws, size_t ws_size,
                              hipStream_t stream) {
    const float* x    = (const float*)d_in[0];
    const float* Wih1 = (const float*)d_in[1];
    const float* Whh1 = (const float*)d_in[2];
    const float* bih1 = (const float*)d_in[3];
    const float* bhh1 = (const float*)d_in[4];
    const float* Wih2 = (const float*)d_in[5];
    const float* Whh2 = (const float*)d_in[6];
    const float* bih2 = (const float*)d_in[7];
    const float* bhh2 = (const float*)d_in[8];
    const float* Wlin = (const float*)d_in[9];
    const float* blin = (const float*)d_in[10];
    float* out = (float*)d_out;

    int*   barA  = (int*)d_ws;                       // monotonic counter A
    int*   barB  = barA + 512;                       // monotonic counter B
    float* h1buf = (float*)((char*)d_ws + 4096);     // legacy fallback state
    float* h2buf = h1buf + 2 * DIM_H;

    lstm_init<<<16, 256, 0, stream>>>(barA, h1buf, h2buf);

    // Workspace layout
    size_t off = WS_WEIGHT_OFF;
    __half* hWih1 = (__half*)((char*)d_ws + off); off += sizeof(__half) * (size_t)N_WIH1;
    __half* hWhh1 = (__half*)((char*)d_ws + off); off += sizeof(__half) * (size_t)N_WHH1;
    __half* hWih2 = (__half*)((char*)d_ws + off); off += sizeof(__half) * (size_t)N_WIH2;
    __half* hWhh2 = (__half*)((char*)d_ws + off); off += sizeof(__half) * (size_t)N_WHH2;
    __half* hWlin = (__half*)((char*)d_ws + off); off += sizeof(__half) * (size_t)N_WLIN;
    const size_t need_w = off;
    float* Gbuf   = (float*)((char*)d_ws + off); off += sizeof(float) * (size_t)T_STEPS * DIM_H4;
    float* h1_all = (float*)((char*)d_ws + off); off += sizeof(float) * (size_t)T_STEPS * DIM_H;
    float* h2_all = (float*)((char*)d_ws + off); off += sizeof(float) * (size_t)T_STEPS * DIM_H;
    const size_t need_full = off;

    const bool have_w    = (ws_size >= need_w);
    const bool have_full = (ws_size >= need_full);

    if (have_w) {
        const float* srcs[5] = { Wih1, Whh1, Wih2, Whh2, Wlin };
        __half*      dsts[5] = { hWih1, hWhh1, hWih2, hWhh2, hWlin };
        const int    ns[5]   = { N_WIH1, N_WHH1, N_WIH2, N_WHH2, N_WLIN };
        for (int m = 0; m < 5; ++m) {
            int n4 = ns[m] / 4;
            convert_f16<<<(n4 + 255) / 256, 256, 0, stream>>>(srcs[m], dsts[m], n4);
        }
    }

    // Fallback argument blocks (streaming paths).
    const __half* cWih1 = hWih1; const __half* cWhh1 = hWhh1;
    const __half* cWih2 = hWih2; const __half* cWhh2 = hWhh2;
    const __half* cWlin = hWlin;
    void* argsH[] = {
        (void*)&x,
        (void*)&cWih1, (void*)&cWhh1, (void*)&bih1, (void*)&bhh1,
        (void*)&cWih2, (void*)&cWhh2, (void*)&bih2, (void*)&bhh2,
        (void*)&cWlin, (void*)&blin,
        (void*)&out, (void*)&barA, (void*)&h1buf, (void*)&h2buf
    };
    void* argsF[] = {
        (void*)&x,
        (void*)&Wih1, (void*)&Whh1, (void*)&bih1, (void*)&bhh1,
        (void*)&Wih2, (void*)&Whh2, (void*)&bih2, (void*)&bhh2,
        (void*)&Wlin, (void*)&blin,
        (void*)&out, (void*)&barA, (void*)&h1buf, (void*)&h2buf
    };

    if (have_full) {
        // Phase 1: G = x @ Wih1^T   [T x 4H], K = D
        gemm_xwT<<<dim3(DIM_H4 / GT_N, T_STEPS / GT_M), 256, 0, stream>>>(
            x, hWih1, nullptr, Gbuf, T_STEPS, DIM_H4, DIM_D, 0);

        // Phase 2: sweep A (h1 recurrence, Whh1 in LDS)
        const float* gA = Gbuf; const __half* wA = hWhh1;
        float* hA = h1_all; int* bA = barA;
        void* argsA[] = { (void*)&gA, (void*)&wA, (void*)&bih1, (void*)&bhh1,
                          (void*)&hA, (void*)&bA };
        hipError_t e = hipLaunchCooperativeKernel((const void*)lstm_sweep,
                                                  dim3(256), dim3(NTHR), argsA, 0, stream);
        if (e == hipSuccess) {
            // Phase 3: G = h1_all @ Wih2^T   [T x 4H], K = H
            gemm_xwT<<<dim3(DIM_H4 / GT_N, T_STEPS / GT_M), 256, 0, stream>>>(
                h1_all, hWih2, nullptr, Gbuf, T_STEPS, DIM_H4, DIM_H, 0);

            // Phase 4: sweep B (h2 recurrence, Whh2 in LDS)
            const float* gB = Gbuf; const __half* wB = hWhh2;
            float* hB = h2_all; int* bB = barB;
            void* argsB[] = { (void*)&gB, (void*)&wB, (void*)&bih2, (void*)&bhh2,
                              (void*)&hB, (void*)&bB };
            hipLaunchCooperativeKernel((const void*)lstm_sweep,
                                       dim3(256), dim3(NTHR), argsB, 0, stream);

            // Phase 5: out = h2_all @ Wlin^T + blin   [T x OUT], K = H
            gemm_xwT<<<dim3(DIM_OUT / GT_N, T_STEPS / GT_M), 256, 0, stream>>>(
                h2_all, hWlin, blin, out, T_STEPS, DIM_OUT, DIM_H, 1);
        } else {
            // Cooperative validation failed: proven fp16 streaming fallback.
            hipLaunchCooperativeKernel((const void*)lstm_stream<__half>,
                                       dim3(256), dim3(NTHR), argsH, 0, stream);
        }
    } else if (have_w) {
        hipLaunchCooperativeKernel((const void*)lstm_stream<__half>,
                                   dim3(256), dim3(NTHR), argsH, 0, stream);
    } else {
        hipLaunchCooperativeKernel((const void*)lstm_stream<float>,
                                   dim3(256), dim3(NTHR), argsF, 0, stream);
    }
}

// Round 9
// 37266.684 us; speedup vs baseline: 1.4348x; 1.4348x over previous
//
#include <hip/hip_runtime.h>
#include <hip/hip_fp16.h>

// LSTM_54537494725306: 2-layer LSTM, T=2048, D=512, H=2048, OUT=64, fp32 in/out.
// R11 = R9/R10 temporal-split structure with a one-hop flat barrier.
// R10 post-mortem: single monotonic counter = 256 RMWs + 256 pollers on ONE
// line -> contention serialization, step 11.9-21.7us (worse than R9's 9.4).
// R11 barrier: 32 distributed group counters (8 WGs each, one line apart,
// max 8 RMWs/line/step) + parallel-lane detection (wave 0: lane i polls
// counter i, exit when __all(cnt >= 8*(t+1))). Critical path = last WG's
// single atomicAdd -> poll detect. No root hop, no flag-store hop.
// Split-phase G[t+1] prefetch kept between arrive and wait; final-step
// barrier skipped (kernel boundary syncs).
// Phases: GEMM1 (x@Wih1^T) -> sweepA (Whh1 in 128KiB LDS/CU) -> GEMM2
// (h1@Wih2^T) -> sweepB (Whh2 in LDS) -> GEMMY (h2@Wlin^T + b).
// Math identical to R9/R10 (fp16 weights -> f32 cvt -> f32 fmaf chains).

#define T_STEPS 2048
#define DIM_D   512
#define DIM_H   2048
#define DIM_H4  8192
#define DIM_OUT 64
#define NTHR    512

#define N_WIH1 (4 * DIM_H * DIM_D)   //  4,194,304
#define N_WHH1 (4 * DIM_H * DIM_H)   // 16,777,216
#define N_WIH2 (4 * DIM_H * DIM_H)
#define N_WHH2 (4 * DIM_H * DIM_H)
#define N_WLIN (DIM_OUT * DIM_H)     //    131,072
#define WS_WEIGHT_OFF 65536

__device__ __forceinline__ float sigf(float x)   { return 1.0f / (1.0f + __expf(-x)); }
__device__ __forceinline__ float tanh_f(float x) { return 1.0f - 2.0f / (__expf(2.0f * x) + 1.0f); }

__device__ __forceinline__ float wave_reduce(float v) {
#pragma unroll
    for (int off = 32; off > 0; off >>= 1) v += __shfl_xor(v, off, 64);
    return v;
}

struct F8 { float4 a, b; };

__device__ __forceinline__ F8 load8(const float* __restrict__ p, int e) {
    F8 r;
    const float4* q = (const float4*)(p + e);
    r.a = q[0]; r.b = q[1];
    return r;
}

__device__ __forceinline__ F8 cvt8(uint4 u) {
    float2 f0 = __half22float2(*(__half2*)&u.x);
    float2 f1 = __half22float2(*(__half2*)&u.y);
    float2 f2 = __half22float2(*(__half2*)&u.z);
    float2 f3 = __half22float2(*(__half2*)&u.w);
    F8 r;
    r.a = make_float4(f0.x, f0.y, f1.x, f1.y);
    r.b = make_float4(f2.x, f2.y, f3.x, f3.y);
    return r;
}

__device__ __forceinline__ F8 load8(const __half* __restrict__ p, int e) {
    uint4 u = *(const uint4*)(p + e);
    return cvt8(u);
}

__device__ __forceinline__ float dot8(const F8& v, const F8& w, float acc) {
    acc = fmaf(v.a.x, w.a.x, acc); acc = fmaf(v.a.y, w.a.y, acc);
    acc = fmaf(v.a.z, w.a.z, acc); acc = fmaf(v.a.w, w.a.w, acc);
    acc = fmaf(v.b.x, w.b.x, acc); acc = fmaf(v.b.y, w.b.y, acc);
    acc = fmaf(v.b.z, w.b.z, acc); acc = fmaf(v.b.w, w.b.w, acc);
    return acc;
}

// 4-row dot over K elements (streaming fallback path only).
template<int K, typename WT>
__device__ __forceinline__ void dot4(const float* __restrict__ v,
                                     const WT* __restrict__ w0, const WT* __restrict__ w1,
                                     const WT* __restrict__ w2, const WT* __restrict__ w3,
                                     int lane, float& a0, float& a1, float& a2, float& a3) {
#pragma unroll
    for (int i = 0; i < K / 512; ++i) {
        const int e = (lane + 64 * i) * 8;
        const F8 vv = load8(v, e);
        a0 = dot8(vv, load8(w0, e), a0);
        a1 = dot8(vv, load8(w1, e), a1);
        a2 = dot8(vv, load8(w2, e), a2);
        a3 = dot8(vv, load8(w3, e), a3);
    }
}

// Two-level sense-free barrier over NGRP*32 workgroups (fallback kernels only).
template<int NGRP>
__device__ __forceinline__ void grid_barrier(int* bar, int wg, int g) {
    __syncthreads();
    if (threadIdx.x == 0) {
        const int grp = wg >> 5;
        int a = __hip_atomic_fetch_add(&bar[grp * 32], 1, __ATOMIC_ACQ_REL, __HIP_MEMORY_SCOPE_AGENT);
        if (a == 31) {
            int r = __hip_atomic_fetch_add(&bar[NGRP * 32], 1, __ATOMIC_ACQ_REL, __HIP_MEMORY_SCOPE_AGENT);
            if (r == NGRP - 1) {
#pragma unroll
                for (int i = 0; i < NGRP; ++i)
                    __hip_atomic_store(&bar[i * 32], 0, __ATOMIC_RELAXED, __HIP_MEMORY_SCOPE_AGENT);
                __hip_atomic_store(&bar[NGRP * 32], 0, __ATOMIC_RELAXED, __HIP_MEMORY_SCOPE_AGENT);
                __hip_atomic_store(&bar[NGRP * 32 + 32], g + 1, __ATOMIC_RELEASE, __HIP_MEMORY_SCOPE_AGENT);
            }
        }
        while (__hip_atomic_load(&bar[NGRP * 32 + 32], __ATOMIC_RELAXED, __HIP_MEMORY_SCOPE_AGENT) <= g) {
            __builtin_amdgcn_s_sleep(2);
        }
        __builtin_amdgcn_fence(__ATOMIC_ACQUIRE, "agent");
    }
    __syncthreads();
}

__global__ void lstm_init(int* bar, float* h1buf, float* h2buf) {
    int i = threadIdx.x + blockIdx.x * blockDim.x;
    if (i < 2048) bar[i] = 0;               // barA [0,1024) + barB [1024,2048)
    if (i < 2 * DIM_H) { h1buf[i] = 0.0f; h2buf[i] = 0.0f; }
}

// fp32 -> fp16 (RNE), 4 elements/thread.
__global__ void convert_f16(const float* __restrict__ src, __half* __restrict__ dst, int n4) {
    int i = threadIdx.x + blockIdx.x * blockDim.x;
    if (i < n4) {
        float4 f = ((const float4*)src)[i];
        __half2 h01 = __floats2half2_rn(f.x, f.y);
        __half2 h23 = __floats2half2_rn(f.z, f.w);
        uint2 o;
        o.x = *(unsigned int*)&h01;
        o.y = *(unsigned int*)&h23;
        ((uint2*)dst)[i] = o;
    }
}

// ---------------------------------------------------------------------------
// GEMM: C[M][N] = A[M][K](fp32) * B[N][K](fp16)^T  (+ bias[n] if hasBias).
// 64x64 tile, 256 threads, 4x4 micro-tile/thread, K-chunks of 32.
// ---------------------------------------------------------------------------
#define GT_M 64
#define GT_N 64
#define GT_K 32

__global__ __launch_bounds__(256) void gemm_xwT(
    const float* __restrict__ A, const __half* __restrict__ B,
    const float* __restrict__ bias, float* __restrict__ C,
    int M, int N, int K, int hasBias)
{
    __shared__ float  As[GT_K][GT_M + 4];   // [32][68] fp32, 8.5 KB
    __shared__ ushort Bs[GT_K][GT_N + 8];   // [32][72] fp16 bits, 4.5 KB

    const int t  = threadIdx.x;
    const int tx = t & 15, ty = t >> 4;
    const int n0 = blockIdx.x * GT_N;
    const int m0 = blockIdx.y * GT_M;

    float acc[4][4];
#pragma unroll
    for (int i = 0; i < 4; ++i)
#pragma unroll
        for (int j = 0; j < 4; ++j) acc[i][j] = 0.f;

    for (int kc = 0; kc < K; kc += GT_K) {
#pragma unroll
        for (int s = 0; s < 2; ++s) {
            const int i  = t + s * 256;
            const int r  = i >> 3;
            const int c4 = (i & 7) * 4;
            const float4 av = *(const float4*)(A + (size_t)(m0 + r) * K + kc + c4);
            As[c4 + 0][r] = av.x; As[c4 + 1][r] = av.y;
            As[c4 + 2][r] = av.z; As[c4 + 3][r] = av.w;
            const uint2 bv = *(const uint2*)(B + (size_t)(n0 + r) * K + kc + c4);
            Bs[c4 + 0][r] = (ushort)(bv.x & 0xffffu);
            Bs[c4 + 1][r] = (ushort)(bv.x >> 16);
            Bs[c4 + 2][r] = (ushort)(bv.y & 0xffffu);
            Bs[c4 + 3][r] = (ushort)(bv.y >> 16);
        }
        __syncthreads();
#pragma unroll
        for (int kk = 0; kk < GT_K; ++kk) {
            const float4 a4 = *(const float4*)&As[kk][ty * 4];
            const uint2  bu = *(const uint2*)&Bs[kk][tx * 4];
            const float2 b01 = __half22float2(*(const __half2*)&bu.x);
            const float2 b23 = __half22float2(*(const __half2*)&bu.y);
            const float a0 = a4.x, a1 = a4.y, a2 = a4.z, a3 = a4.w;
            const float b0 = b01.x, b1 = b01.y, b2 = b23.x, b3 = b23.y;
            acc[0][0] = fmaf(a0, b0, acc[0][0]); acc[0][1] = fmaf(a0, b1, acc[0][1]);
            acc[0][2] = fmaf(a0, b2, acc[0][2]); acc[0][3] = fmaf(a0, b3, acc[0][3]);
            acc[1][0] = fmaf(a1, b0, acc[1][0]); acc[1][1] = fmaf(a1, b1, acc[1][1]);
            acc[1][2] = fmaf(a1, b2, acc[1][2]); acc[1][3] = fmaf(a1, b3, acc[1][3]);
            acc[2][0] = fmaf(a2, b0, acc[2][0]); acc[2][1] = fmaf(a2, b1, acc[2][1]);
            acc[2][2] = fmaf(a2, b2, acc[2][2]); acc[2][3] = fmaf(a2, b3, acc[2][3]);
            acc[3][0] = fmaf(a3, b0, acc[3][0]); acc[3][1] = fmaf(a3, b1, acc[3][1]);
            acc[3][2] = fmaf(a3, b2, acc[3][2]); acc[3][3] = fmaf(a3, b3, acc[3][3]);
        }
        __syncthreads();
    }

    float4 bv = make_float4(0.f, 0.f, 0.f, 0.f);
    if (hasBias) {
        const int n = n0 + tx * 4;
        bv = make_float4(bias[n], bias[n + 1], bias[n + 2], bias[n + 3]);
    }
#pragma unroll
    for (int i = 0; i < 4; ++i) {
        const int m = m0 + ty * 4 + i;
        float4 v = make_float4(acc[i][0] + bv.x, acc[i][1] + bv.y,
                               acc[i][2] + bv.z, acc[i][3] + bv.w);
        *(float4*)(C + (size_t)m * N + n0 + tx * 4) = v;
    }
}

// ---------------------------------------------------------------------------
// Sequential sweep, flat one-hop barrier.
// 256 WGs x 512 thr (8 waves), 1 wave/unit; Whh rows in 128 KiB LDS/CU.
// Arrive: leader atomicAdd to group counter (32 groups of 8 WGs, 1 line each).
// Wait: wave 0, lane i polls counter i (i<32); exit when __all(cnt>=8*(t+1)).
// ---------------------------------------------------------------------------
__global__ __launch_bounds__(NTHR, 2) void lstm_sweep(
    const float* __restrict__ G,     // [T][4H] x-part pre-activations
    const __half* __restrict__ Whh,  // [4H][H] fp16
    const float* __restrict__ bi, const float* __restrict__ bh,
    float* __restrict__ h_all,       // [T][H]
    int* bar)                        // 32 monotonic counters at bar[g*32]
{
    const int wg   = blockIdx.x;
    const int wave = threadIdx.x >> 6;
    const int lane = threadIdx.x & 63;
    const int unit = wg * 8 + wave;
    const int grp  = wg >> 3;        // 32 groups of 8 WGs

    __shared__ uint4 ldsW[8][4][DIM_H / 8];   // 131072 B

#pragma unroll
    for (int g = 0; g < 4; ++g) {
        const uint4* q = (const uint4*)(Whh + (size_t)(g * DIM_H + unit) * DIM_H);
#pragma unroll
        for (int j = 0; j < 4; ++j)
            ldsW[wave][g][lane + 64 * j] = q[lane + 64 * j];
    }
    const float b0 = bi[0 * DIM_H + unit] + bh[0 * DIM_H + unit];
    const float b1 = bi[1 * DIM_H + unit] + bh[1 * DIM_H + unit];
    const float b2 = bi[2 * DIM_H + unit] + bh[2 * DIM_H + unit];
    const float b3 = bi[3 * DIM_H + unit] + bh[3 * DIM_H + unit];
    __syncthreads();

    float c = 0.0f;

    // G[0] preloaded (same-address across lanes -> broadcast).
    float g0 = G[0 * DIM_H + unit];
    float g1 = G[1 * DIM_H + unit];
    float g2 = G[2 * DIM_H + unit];
    float g3 = G[3 * DIM_H + unit];

    for (int t = 0; t < T_STEPS; ++t) {
        float a0 = 0.f, a1 = 0.f, a2 = 0.f, a3 = 0.f;
        if (t > 0) {
            const float* hp = h_all + (size_t)(t - 1) * DIM_H;
#pragma unroll
            for (int j = 0; j < 4; ++j) {
                const F8 hv = load8(hp, (lane + 64 * j) * 8);
                a0 = dot8(hv, cvt8(ldsW[wave][0][lane + 64 * j]), a0);
                a1 = dot8(hv, cvt8(ldsW[wave][1][lane + 64 * j]), a1);
                a2 = dot8(hv, cvt8(ldsW[wave][2][lane + 64 * j]), a2);
                a3 = dot8(hv, cvt8(ldsW[wave][3][lane + 64 * j]), a3);
            }
            a0 = wave_reduce(a0); a1 = wave_reduce(a1);
            a2 = wave_reduce(a2); a3 = wave_reduce(a3);
        }

        const float gi = sigf  (a0 + g0 + b0);
        const float gf = sigf  (a1 + g1 + b1);
        const float gg = tanh_f(a2 + g2 + b2);
        const float go = sigf  (a3 + g3 + b3);
        c = fmaf(gf, c, gi * gg);
        const float hv = go * tanh_f(c);
        if (lane == 0) h_all[(size_t)t * DIM_H + unit] = hv;

        if (t + 1 >= T_STEPS) break;   // kernel boundary syncs the final step

        // ---- arrive (after h store drains via syncthreads' vmcnt wait) ----
        __syncthreads();
        if (threadIdx.x == 0)
            __hip_atomic_fetch_add(&bar[grp * 32], 1, __ATOMIC_ACQ_REL, __HIP_MEMORY_SCOPE_AGENT);

        // ---- prefetch next-step G while the grid converges ----
        const size_t nb = (size_t)(t + 1) * DIM_H4;
        const float n0 = G[nb + 0 * DIM_H + unit];
        const float n1 = G[nb + 1 * DIM_H + unit];
        const float n2 = G[nb + 2 * DIM_H + unit];
        const float n3 = G[nb + 3 * DIM_H + unit];

        // ---- wait: lane i polls group counter i; all must reach 8*(t+1) ----
        if (wave == 0) {
            const int tgt = 8 * (t + 1);
            for (;;) {
                int v = tgt;
                if (lane < 32)
                    v = __hip_atomic_load(&bar[lane * 32], __ATOMIC_RELAXED, __HIP_MEMORY_SCOPE_AGENT);
                if (__all(v >= tgt)) break;
                __builtin_amdgcn_s_sleep(1);
            }
            if (lane == 0)
                __builtin_amdgcn_fence(__ATOMIC_ACQUIRE, "agent");
        }
        __syncthreads();

        g0 = n0; g1 = n1; g2 = n2; g3 = n3;
    }
}

// ---------------------------------------------------------------------------
// Fallback: R2-style weight streaming, 256 WGs x 8 waves (proven correct).
// ---------------------------------------------------------------------------
template<typename WT>
__global__ __launch_bounds__(NTHR, 2) void lstm_stream(
    const float* __restrict__ x,
    const WT* __restrict__ Wih1, const WT* __restrict__ Whh1,
    const float* __restrict__ bih1, const float* __restrict__ bhh1,
    const WT* __restrict__ Wih2, const WT* __restrict__ Whh2,
    const float* __restrict__ bih2, const float* __restrict__ bhh2,
    const WT* __restrict__ Wlin, const float* __restrict__ blin,
    float* __restrict__ out,
    int* bar, float* h1buf, float* h2buf)
{
    const int wg   = blockIdx.x;
    const int wave = threadIdx.x >> 6;
    const int lane = threadIdx.x & 63;
    const int unit = wg * 8 + wave;

    const int r0 = unit, r1 = DIM_H + unit, r2 = 2 * DIM_H + unit, r3 = 3 * DIM_H + unit;
    const float b1_0 = bih1[r0] + bhh1[r0];
    const float b1_1 = bih1[r1] + bhh1[r1];
    const float b1_2 = bih1[r2] + bhh1[r2];
    const float b1_3 = bih1[r3] + bhh1[r3];
    const float b2_0 = bih2[r0] + bhh2[r0];
    const float b2_1 = bih2[r1] + bhh2[r1];
    const float b2_2 = bih2[r2] + bhh2[r2];
    const float b2_3 = bih2[r3] + bhh2[r3];

    const WT* wi1_0 = Wih1 + (size_t)r0 * DIM_D;
    const WT* wi1_1 = Wih1 + (size_t)r1 * DIM_D;
    const WT* wi1_2 = Wih1 + (size_t)r2 * DIM_D;
    const WT* wi1_3 = Wih1 + (size_t)r3 * DIM_D;
    const WT* wh1_0 = Whh1 + (size_t)r0 * DIM_H;
    const WT* wh1_1 = Whh1 + (size_t)r1 * DIM_H;
    const WT* wh1_2 = Whh1 + (size_t)r2 * DIM_H;
    const WT* wh1_3 = Whh1 + (size_t)r3 * DIM_H;
    const WT* wi2_0 = Wih2 + (size_t)r0 * DIM_H;
    const WT* wi2_1 = Wih2 + (size_t)r1 * DIM_H;
    const WT* wi2_2 = Wih2 + (size_t)r2 * DIM_H;
    const WT* wi2_3 = Wih2 + (size_t)r3 * DIM_H;
    const WT* wh2_0 = Whh2 + (size_t)r0 * DIM_H;
    const WT* wh2_1 = Whh2 + (size_t)r1 * DIM_H;
    const WT* wh2_2 = Whh2 + (size_t)r2 * DIM_H;
    const WT* wh2_3 = Whh2 + (size_t)r3 * DIM_H;

    const bool  do_y = (wg < DIM_OUT) && (wave == 0);
    const float by   = (wg < DIM_OUT) ? blin[wg] : 0.0f;
    const WT*   wy   = Wlin + (size_t)(wg < DIM_OUT ? wg : 0) * DIM_H;

    float c1 = 0.0f, c2 = 0.0f;

    for (int p = 0; p < T_STEPS + 2; ++p) {
        const float* h1_prev  = h1buf + (size_t)((p + 1) & 1) * DIM_H;
        float*       h1_cur   = h1buf + (size_t)(p & 1) * DIM_H;
        const float* h2_prev2 = h2buf + (size_t)(p & 1) * DIM_H;
        float*       h2_cur   = h2buf + (size_t)((p + 1) & 1) * DIM_H;

        if (p < T_STEPS) {
            float a0 = 0.f, a1 = 0.f, a2 = 0.f, a3 = 0.f;
            dot4<DIM_D>(x + (size_t)p * DIM_D, wi1_0, wi1_1, wi1_2, wi1_3, lane, a0, a1, a2, a3);
            dot4<DIM_H>(h1_prev, wh1_0, wh1_1, wh1_2, wh1_3, lane, a0, a1, a2, a3);
            a0 = wave_reduce(a0); a1 = wave_reduce(a1);
            a2 = wave_reduce(a2); a3 = wave_reduce(a3);
            const float gi = sigf(a0 + b1_0);
            const float gf = sigf(a1 + b1_1);
            const float gg = tanh_f(a2 + b1_2);
            const float go = sigf(a3 + b1_3);
            c1 = fmaf(gf, c1, gi * gg);
            if (lane == 0) h1_cur[unit] = go * tanh_f(c1);
        }

        if (p >= 1 && p <= T_STEPS) {
            float a0 = 0.f, a1 = 0.f, a2 = 0.f, a3 = 0.f;
            dot4<DIM_H>(h1_prev,  wi2_0, wi2_1, wi2_2, wi2_3, lane, a0, a1, a2, a3);
            dot4<DIM_H>(h2_prev2, wh2_0, wh2_1, wh2_2, wh2_3, lane, a0, a1, a2, a3);
            a0 = wave_reduce(a0); a1 = wave_reduce(a1);
            a2 = wave_reduce(a2); a3 = wave_reduce(a3);
            const float gi = sigf(a0 + b2_0);
            const float gf = sigf(a1 + b2_1);
            const float gg = tanh_f(a2 + b2_2);
            const float go = sigf(a3 + b2_3);
            c2 = fmaf(gf, c2, gi * gg);
            if (lane == 0) h2_cur[unit] = go * tanh_f(c2);
        }

        if (do_y && p >= 2) {
            float a = 0.f;
#pragma unroll
            for (int i = 0; i < DIM_H / 512; ++i) {
                const int e = (lane + 64 * i) * 8;
                a = dot8(load8(h2_prev2, e), load8(wy, e), a);
            }
            a = wave_reduce(a);
            if (lane == 0) out[(size_t)(p - 2) * DIM_OUT + wg] = a + by;
        }

        grid_barrier<8>(bar, wg, p);
    }
}

extern "C" void kernel_launch(void* const* d_in, const int* in_sizes, int n_in,
                              void* d_out, int out_size, void* d_ws, size_t ws_size,
                              hipStream_t stream) {
    const float* x    = (const float*)d_in[0];
    const float* Wih1 = (const float*)d_in[1];
    const float* Whh1 = (const float*)d_in[2];
    const float* bih1 = (const float*)d_in[3];
    const float* bhh1 = (const float*)d_in[4];
    const float* Wih2 = (const float*)d_in[5];
    const float* Whh2 = (const float*)d_in[6];
    const float* bih2 = (const float*)d_in[7];
    const float* bhh2 = (const float*)d_in[8];
    const float* Wlin = (const float*)d_in[9];
    const float* blin = (const float*)d_in[10];
    float* out = (float*)d_out;

    int*   barA  = (int*)d_ws;                       // 32 counters, ints [0,1024)
    int*   barB  = barA + 1024;                      // 32 counters, ints [1024,2048)
    float* h1buf = (float*)((char*)d_ws + 8192);     // legacy fallback state
    float* h2buf = h1buf + 2 * DIM_H;

    lstm_init<<<16, 256, 0, stream>>>(barA, h1buf, h2buf);

    // Workspace layout
    size_t off = WS_WEIGHT_OFF;
    __half* hWih1 = (__half*)((char*)d_ws + off); off += sizeof(__half) * (size_t)N_WIH1;
    __half* hWhh1 = (__half*)((char*)d_ws + off); off += sizeof(__half) * (size_t)N_WHH1;
    __half* hWih2 = (__half*)((char*)d_ws + off); off += sizeof(__half) * (size_t)N_WIH2;
    __half* hWhh2 = (__half*)((char*)d_ws + off); off += sizeof(__half) * (size_t)N_WHH2;
    __half* hWlin = (__half*)((char*)d_ws + off); off += sizeof(__half) * (size_t)N_WLIN;
    const size_t need_w = off;
    float* Gbuf   = (float*)((char*)d_ws + off); off += sizeof(float) * (size_t)T_STEPS * DIM_H4;
    float* h1_all = (float*)((char*)d_ws + off); off += sizeof(float) * (size_t)T_STEPS * DIM_H;
    float* h2_all = (float*)((char*)d_ws + off); off += sizeof(float) * (size_t)T_STEPS * DIM_H;
    const size_t need_full = off;

    const bool have_w    = (ws_size >= need_w);
    const bool have_full = (ws_size >= need_full);

    if (have_w) {
        const float* srcs[5] = { Wih1, Whh1, Wih2, Whh2, Wlin };
        __half*      dsts[5] = { hWih1, hWhh1, hWih2, hWhh2, hWlin };
        const int    ns[5]   = { N_WIH1, N_WHH1, N_WIH2, N_WHH2, N_WLIN };
        for (int m = 0; m < 5; ++m) {
            int n4 = ns[m] / 4;
            convert_f16<<<(n4 + 255) / 256, 256, 0, stream>>>(srcs[m], dsts[m], n4);
        }
    }

    // Fallback argument blocks (streaming paths).
    const __half* cWih1 = hWih1; const __half* cWhh1 = hWhh1;
    const __half* cWih2 = hWih2; const __half* cWhh2 = hWhh2;
    const __half* cWlin = hWlin;
    void* argsH[] = {
        (void*)&x,
        (void*)&cWih1, (void*)&cWhh1, (void*)&bih1, (void*)&bhh1,
        (void*)&cWih2, (void*)&cWhh2, (void*)&bih2, (void*)&bhh2,
        (void*)&cWlin, (void*)&blin,
        (void*)&out, (void*)&barA, (void*)&h1buf, (void*)&h2buf
    };
    void* argsF[] = {
        (void*)&x,
        (void*)&Wih1, (void*)&Whh1, (void*)&bih1, (void*)&bhh1,
        (void*)&Wih2, (void*)&Whh2, (void*)&bih2, (void*)&bhh2,
        (void*)&Wlin, (void*)&blin,
        (void*)&out, (void*)&barA, (void*)&h1buf, (void*)&h2buf
    };

    if (have_full) {
        // Phase 1: G = x @ Wih1^T   [T x 4H], K = D
        gemm_xwT<<<dim3(DIM_H4 / GT_N, T_STEPS / GT_M), 256, 0, stream>>>(
            x, hWih1, nullptr, Gbuf, T_STEPS, DIM_H4, DIM_D, 0);

        // Phase 2: sweep A (h1 recurrence, Whh1 in LDS)
        const float* gA = Gbuf; const __half* wA = hWhh1;
        float* hA = h1_all; int* bA = barA;
        void* argsA[] = { (void*)&gA, (void*)&wA, (void*)&bih1, (void*)&bhh1,
                          (void*)&hA, (void*)&bA };
        hipError_t e = hipLaunchCooperativeKernel((const void*)lstm_sweep,
                                                  dim3(256), dim3(NTHR), argsA, 0, stream);
        if (e == hipSuccess) {
            // Phase 3: G = h1_all @ Wih2^T   [T x 4H], K = H
            gemm_xwT<<<dim3(DIM_H4 / GT_N, T_STEPS / GT_M), 256, 0, stream>>>(
                h1_all, hWih2, nullptr, Gbuf, T_STEPS, DIM_H4, DIM_H, 0);

            // Phase 4: sweep B (h2 recurrence, Whh2 in LDS)
            const float* gB = Gbuf; const __half* wB = hWhh2;
            float* hB = h2_all; int* bB = barB;
            void* argsB[] = { (void*)&gB, (void*)&wB, (void*)&bih2, (void*)&bhh2,
                              (void*)&hB, (void*)&bB };
            hipLaunchCooperativeKernel((const void*)lstm_sweep,
                                       dim3(256), dim3(NTHR), argsB, 0, stream);

            // Phase 5: out = h2_all @ Wlin^T + blin   [T x OUT], K = H
            gemm_xwT<<<dim3(DIM_OUT / GT_N, T_STEPS / GT_M), 256, 0, stream>>>(
                h2_all, hWlin, blin, out, T_STEPS, DIM_OUT, DIM_H, 1);
        } else {
            // Cooperative validation failed: proven fp16 streaming fallback.
            hipLaunchCooperativeKernel((const void*)lstm_stream<__half>,
                                       dim3(256), dim3(NTHR), argsH, 0, stream);
        }
    } else if (have_w) {
        hipLaunchCooperativeKernel((const void*)lstm_stream<__half>,
                                   dim3(256), dim3(NTHR), argsH, 0, stream);
    } else {
        hipLaunchCooperativeKernel((const void*)lstm_stream<float>,
                                   dim3(256), dim3(NTHR), argsF, 0, stream);
    }
}

// Round 10
// 35711.557 us; speedup vs baseline: 1.4973x; 1.0435x over previous
//
#include <hip/hip_runtime.h>
#include <hip/hip_fp16.h>

// LSTM_54537494725306: 2-layer LSTM, T=2048, D=512, H=2048, OUT=64, fp32 in/out.
// R12 = R11 temporal-split + flat barrier, with the per-step acquire fence
// ELIMINATED. R11 post-mortem: step 8.7us vs ~0.7us compute; FETCH 160KB/step
// vs 40KB true read-set -> the agent-scope acquire fence invalidates L1/L2
// every step (G/weight/h refetch + cold post-detect h load) and dominates.
// R12: cross-WG data (h_all) moves to the coherence point via RELAXED
// agent-scope atomics (cache-bypass, cross-XCD coherent):
//   * producer: lane0 atomic-store h (relaxed, agent)
//   * arrival RMW keeps ACQ_REL (release = vmcnt drain; orders h-store
//     before counter bump at the coherence point; no cache maintenance)
//   * consumer: poll 32 group counters (relaxed) -> compiler barrier ->
//     atomic-load h (relaxed, agent). No acquire fence: atomic loads read
//     the coherence point, which already holds the released h values.
// G loads stay plain/cacheable (produced by a prior kernel; boundary syncs)
// and now stay cached across steps (no invalidates).
// Phases: GEMM1 (x@Wih1^T) -> sweepA (Whh1 in 128KiB LDS/CU) -> GEMM2
// (h1@Wih2^T) -> sweepB (Whh2 in LDS) -> GEMMY (h2@Wlin^T + b).
// Math identical to R9-R11 (fp16 weights -> f32 cvt -> f32 fmaf chains).

#define T_STEPS 2048
#define DIM_D   512
#define DIM_H   2048
#define DIM_H4  8192
#define DIM_OUT 64
#define NTHR    512

#define N_WIH1 (4 * DIM_H * DIM_D)   //  4,194,304
#define N_WHH1 (4 * DIM_H * DIM_H)   // 16,777,216
#define N_WIH2 (4 * DIM_H * DIM_H)
#define N_WHH2 (4 * DIM_H * DIM_H)
#define N_WLIN (DIM_OUT * DIM_H)     //    131,072
#define WS_WEIGHT_OFF 65536

__device__ __forceinline__ float sigf(float x)   { return 1.0f / (1.0f + __expf(-x)); }
__device__ __forceinline__ float tanh_f(float x) { return 1.0f - 2.0f / (__expf(2.0f * x) + 1.0f); }

__device__ __forceinline__ float wave_reduce(float v) {
#pragma unroll
    for (int off = 32; off > 0; off >>= 1) v += __shfl_xor(v, off, 64);
    return v;
}

struct F8 { float4 a, b; };

__device__ __forceinline__ F8 load8(const float* __restrict__ p, int e) {
    F8 r;
    const float4* q = (const float4*)(p + e);
    r.a = q[0]; r.b = q[1];
    return r;
}

// 8 floats via 4 relaxed agent-scope 64-bit atomic loads (coherence-point
// reads; bypass L1/L2 so no acquire fence is needed to see released data).
__device__ __forceinline__ F8 load8_coh(const float* p, int e) {
    const unsigned long long* q = (const unsigned long long*)(p + e);
    unsigned long long u0 = __hip_atomic_load(q + 0, __ATOMIC_RELAXED, __HIP_MEMORY_SCOPE_AGENT);
    unsigned long long u1 = __hip_atomic_load(q + 1, __ATOMIC_RELAXED, __HIP_MEMORY_SCOPE_AGENT);
    unsigned long long u2 = __hip_atomic_load(q + 2, __ATOMIC_RELAXED, __HIP_MEMORY_SCOPE_AGENT);
    unsigned long long u3 = __hip_atomic_load(q + 3, __ATOMIC_RELAXED, __HIP_MEMORY_SCOPE_AGENT);
    F8 r;
    float2 f0 = *(float2*)&u0, f1 = *(float2*)&u1;
    float2 f2 = *(float2*)&u2, f3 = *(float2*)&u3;
    r.a = make_float4(f0.x, f0.y, f1.x, f1.y);
    r.b = make_float4(f2.x, f2.y, f3.x, f3.y);
    return r;
}

__device__ __forceinline__ F8 cvt8(uint4 u) {
    float2 f0 = __half22float2(*(__half2*)&u.x);
    float2 f1 = __half22float2(*(__half2*)&u.y);
    float2 f2 = __half22float2(*(__half2*)&u.z);
    float2 f3 = __half22float2(*(__half2*)&u.w);
    F8 r;
    r.a = make_float4(f0.x, f0.y, f1.x, f1.y);
    r.b = make_float4(f2.x, f2.y, f3.x, f3.y);
    return r;
}

__device__ __forceinline__ F8 load8(const __half* __restrict__ p, int e) {
    uint4 u = *(const uint4*)(p + e);
    return cvt8(u);
}

__device__ __forceinline__ float dot8(const F8& v, const F8& w, float acc) {
    acc = fmaf(v.a.x, w.a.x, acc); acc = fmaf(v.a.y, w.a.y, acc);
    acc = fmaf(v.a.z, w.a.z, acc); acc = fmaf(v.a.w, w.a.w, acc);
    acc = fmaf(v.b.x, w.b.x, acc); acc = fmaf(v.b.y, w.b.y, acc);
    acc = fmaf(v.b.z, w.b.z, acc); acc = fmaf(v.b.w, w.b.w, acc);
    return acc;
}

// 4-row dot over K elements (streaming fallback path only).
template<int K, typename WT>
__device__ __forceinline__ void dot4(const float* __restrict__ v,
                                     const WT* __restrict__ w0, const WT* __restrict__ w1,
                                     const WT* __restrict__ w2, const WT* __restrict__ w3,
                                     int lane, float& a0, float& a1, float& a2, float& a3) {
#pragma unroll
    for (int i = 0; i < K / 512; ++i) {
        const int e = (lane + 64 * i) * 8;
        const F8 vv = load8(v, e);
        a0 = dot8(vv, load8(w0, e), a0);
        a1 = dot8(vv, load8(w1, e), a1);
        a2 = dot8(vv, load8(w2, e), a2);
        a3 = dot8(vv, load8(w3, e), a3);
    }
}

// Two-level sense-free barrier over NGRP*32 workgroups (fallback kernels only).
template<int NGRP>
__device__ __forceinline__ void grid_barrier(int* bar, int wg, int g) {
    __syncthreads();
    if (threadIdx.x == 0) {
        const int grp = wg >> 5;
        int a = __hip_atomic_fetch_add(&bar[grp * 32], 1, __ATOMIC_ACQ_REL, __HIP_MEMORY_SCOPE_AGENT);
        if (a == 31) {
            int r = __hip_atomic_fetch_add(&bar[NGRP * 32], 1, __ATOMIC_ACQ_REL, __HIP_MEMORY_SCOPE_AGENT);
            if (r == NGRP - 1) {
#pragma unroll
                for (int i = 0; i < NGRP; ++i)
                    __hip_atomic_store(&bar[i * 32], 0, __ATOMIC_RELAXED, __HIP_MEMORY_SCOPE_AGENT);
                __hip_atomic_store(&bar[NGRP * 32], 0, __ATOMIC_RELAXED, __HIP_MEMORY_SCOPE_AGENT);
                __hip_atomic_store(&bar[NGRP * 32 + 32], g + 1, __ATOMIC_RELEASE, __HIP_MEMORY_SCOPE_AGENT);
            }
        }
        while (__hip_atomic_load(&bar[NGRP * 32 + 32], __ATOMIC_RELAXED, __HIP_MEMORY_SCOPE_AGENT) <= g) {
            __builtin_amdgcn_s_sleep(2);
        }
        __builtin_amdgcn_fence(__ATOMIC_ACQUIRE, "agent");
    }
    __syncthreads();
}

__global__ void lstm_init(int* bar, float* h1buf, float* h2buf) {
    int i = threadIdx.x + blockIdx.x * blockDim.x;
    if (i < 2048) bar[i] = 0;               // barA [0,1024) + barB [1024,2048)
    if (i < 2 * DIM_H) { h1buf[i] = 0.0f; h2buf[i] = 0.0f; }
}

// fp32 -> fp16 (RNE), 4 elements/thread.
__global__ void convert_f16(const float* __restrict__ src, __half* __restrict__ dst, int n4) {
    int i = threadIdx.x + blockIdx.x * blockDim.x;
    if (i < n4) {
        float4 f = ((const float4*)src)[i];
        __half2 h01 = __floats2half2_rn(f.x, f.y);
        __half2 h23 = __floats2half2_rn(f.z, f.w);
        uint2 o;
        o.x = *(unsigned int*)&h01;
        o.y = *(unsigned int*)&h23;
        ((uint2*)dst)[i] = o;
    }
}

// ---------------------------------------------------------------------------
// GEMM: C[M][N] = A[M][K](fp32) * B[N][K](fp16)^T  (+ bias[n] if hasBias).
// 64x64 tile, 256 threads, 4x4 micro-tile/thread, K-chunks of 32.
// ---------------------------------------------------------------------------
#define GT_M 64
#define GT_N 64
#define GT_K 32

__global__ __launch_bounds__(256) void gemm_xwT(
    const float* __restrict__ A, const __half* __restrict__ B,
    const float* __restrict__ bias, float* __restrict__ C,
    int M, int N, int K, int hasBias)
{
    __shared__ float  As[GT_K][GT_M + 4];   // [32][68] fp32, 8.5 KB
    __shared__ ushort Bs[GT_K][GT_N + 8];   // [32][72] fp16 bits, 4.5 KB

    const int t  = threadIdx.x;
    const int tx = t & 15, ty = t >> 4;
    const int n0 = blockIdx.x * GT_N;
    const int m0 = blockIdx.y * GT_M;

    float acc[4][4];
#pragma unroll
    for (int i = 0; i < 4; ++i)
#pragma unroll
        for (int j = 0; j < 4; ++j) acc[i][j] = 0.f;

    for (int kc = 0; kc < K; kc += GT_K) {
#pragma unroll
        for (int s = 0; s < 2; ++s) {
            const int i  = t + s * 256;
            const int r  = i >> 3;
            const int c4 = (i & 7) * 4;
            const float4 av = *(const float4*)(A + (size_t)(m0 + r) * K + kc + c4);
            As[c4 + 0][r] = av.x; As[c4 + 1][r] = av.y;
            As[c4 + 2][r] = av.z; As[c4 + 3][r] = av.w;
            const uint2 bv = *(const uint2*)(B + (size_t)(n0 + r) * K + kc + c4);
            Bs[c4 + 0][r] = (ushort)(bv.x & 0xffffu);
            Bs[c4 + 1][r] = (ushort)(bv.x >> 16);
            Bs[c4 + 2][r] = (ushort)(bv.y & 0xffffu);
            Bs[c4 + 3][r] = (ushort)(bv.y >> 16);
        }
        __syncthreads();
#pragma unroll
        for (int kk = 0; kk < GT_K; ++kk) {
            const float4 a4 = *(const float4*)&As[kk][ty * 4];
            const uint2  bu = *(const uint2*)&Bs[kk][tx * 4];
            const float2 b01 = __half22float2(*(const __half2*)&bu.x);
            const float2 b23 = __half22float2(*(const __half2*)&bu.y);
            const float a0 = a4.x, a1 = a4.y, a2 = a4.z, a3 = a4.w;
            const float b0 = b01.x, b1 = b01.y, b2 = b23.x, b3 = b23.y;
            acc[0][0] = fmaf(a0, b0, acc[0][0]); acc[0][1] = fmaf(a0, b1, acc[0][1]);
            acc[0][2] = fmaf(a0, b2, acc[0][2]); acc[0][3] = fmaf(a0, b3, acc[0][3]);
            acc[1][0] = fmaf(a1, b0, acc[1][0]); acc[1][1] = fmaf(a1, b1, acc[1][1]);
            acc[1][2] = fmaf(a1, b2, acc[1][2]); acc[1][3] = fmaf(a1, b3, acc[1][3]);
            acc[2][0] = fmaf(a2, b0, acc[2][0]); acc[2][1] = fmaf(a2, b1, acc[2][1]);
            acc[2][2] = fmaf(a2, b2, acc[2][2]); acc[2][3] = fmaf(a2, b3, acc[2][3]);
            acc[3][0] = fmaf(a3, b0, acc[3][0]); acc[3][1] = fmaf(a3, b1, acc[3][1]);
            acc[3][2] = fmaf(a3, b2, acc[3][2]); acc[3][3] = fmaf(a3, b3, acc[3][3]);
        }
        __syncthreads();
    }

    float4 bv = make_float4(0.f, 0.f, 0.f, 0.f);
    if (hasBias) {
        const int n = n0 + tx * 4;
        bv = make_float4(bias[n], bias[n + 1], bias[n + 2], bias[n + 3]);
    }
#pragma unroll
    for (int i = 0; i < 4; ++i) {
        const int m = m0 + ty * 4 + i;
        float4 v = make_float4(acc[i][0] + bv.x, acc[i][1] + bv.y,
                               acc[i][2] + bv.z, acc[i][3] + bv.w);
        *(float4*)(C + (size_t)m * N + n0 + tx * 4) = v;
    }
}

// ---------------------------------------------------------------------------
// Sequential sweep, flat one-hop barrier, fence-free h exchange.
// 256 WGs x 512 thr (8 waves), 1 wave/unit; Whh rows in 128 KiB LDS/CU.
// h_all accessed with relaxed agent atomics (coherence point); arrival RMW
// release-orders the h store; NO acquire fence after detection.
// ---------------------------------------------------------------------------
__global__ __launch_bounds__(NTHR, 2) void lstm_sweep(
    const float* __restrict__ G,     // [T][4H] x-part pre-activations
    const __half* __restrict__ Whh,  // [4H][H] fp16
    const float* __restrict__ bi, const float* __restrict__ bh,
    float* __restrict__ h_all,       // [T][H]
    int* bar)                        // 32 monotonic counters at bar[g*32]
{
    const int wg   = blockIdx.x;
    const int wave = threadIdx.x >> 6;
    const int lane = threadIdx.x & 63;
    const int unit = wg * 8 + wave;
    const int grp  = wg >> 3;        // 32 groups of 8 WGs

    __shared__ uint4 ldsW[8][4][DIM_H / 8];   // 131072 B

#pragma unroll
    for (int g = 0; g < 4; ++g) {
        const uint4* q = (const uint4*)(Whh + (size_t)(g * DIM_H + unit) * DIM_H);
#pragma unroll
        for (int j = 0; j < 4; ++j)
            ldsW[wave][g][lane + 64 * j] = q[lane + 64 * j];
    }
    const float b0 = bi[0 * DIM_H + unit] + bh[0 * DIM_H + unit];
    const float b1 = bi[1 * DIM_H + unit] + bh[1 * DIM_H + unit];
    const float b2 = bi[2 * DIM_H + unit] + bh[2 * DIM_H + unit];
    const float b3 = bi[3 * DIM_H + unit] + bh[3 * DIM_H + unit];
    __syncthreads();

    float c = 0.0f;

    // G[0] preloaded (same-address across lanes -> broadcast).
    float g0 = G[0 * DIM_H + unit];
    float g1 = G[1 * DIM_H + unit];
    float g2 = G[2 * DIM_H + unit];
    float g3 = G[3 * DIM_H + unit];

    for (int t = 0; t < T_STEPS; ++t) {
        float a0 = 0.f, a1 = 0.f, a2 = 0.f, a3 = 0.f;
        if (t > 0) {
            const float* hp = h_all + (size_t)(t - 1) * DIM_H;
#pragma unroll
            for (int j = 0; j < 4; ++j) {
                const F8 hv = load8_coh(hp, (lane + 64 * j) * 8);
                a0 = dot8(hv, cvt8(ldsW[wave][0][lane + 64 * j]), a0);
                a1 = dot8(hv, cvt8(ldsW[wave][1][lane + 64 * j]), a1);
                a2 = dot8(hv, cvt8(ldsW[wave][2][lane + 64 * j]), a2);
                a3 = dot8(hv, cvt8(ldsW[wave][3][lane + 64 * j]), a3);
            }
            a0 = wave_reduce(a0); a1 = wave_reduce(a1);
            a2 = wave_reduce(a2); a3 = wave_reduce(a3);
        }

        const float gi = sigf  (a0 + g0 + b0);
        const float gf = sigf  (a1 + g1 + b1);
        const float gg = tanh_f(a2 + g2 + b2);
        const float go = sigf  (a3 + g3 + b3);
        c = fmaf(gf, c, gi * gg);
        const float hv = go * tanh_f(c);
        if (lane == 0)
            __hip_atomic_store(&h_all[(size_t)t * DIM_H + unit], hv,
                               __ATOMIC_RELAXED, __HIP_MEMORY_SCOPE_AGENT);

        if (t + 1 >= T_STEPS) break;   // kernel boundary syncs the final step

        // ---- arrive: release-RMW orders the h store at the coherence point ----
        __syncthreads();
        if (threadIdx.x == 0)
            __hip_atomic_fetch_add(&bar[grp * 32], 1, __ATOMIC_ACQ_REL, __HIP_MEMORY_SCOPE_AGENT);

        // ---- prefetch next-step G while the grid converges (cacheable) ----
        const size_t nb = (size_t)(t + 1) * DIM_H4;
        const float n0 = G[nb + 0 * DIM_H + unit];
        const float n1 = G[nb + 1 * DIM_H + unit];
        const float n2 = G[nb + 2 * DIM_H + unit];
        const float n3 = G[nb + 3 * DIM_H + unit];

        // ---- wait: lane i polls group counter i; all must reach 8*(t+1) ----
        if (wave == 0) {
            const int tgt = 8 * (t + 1);
            for (;;) {
                int v = tgt;
                if (lane < 32)
                    v = __hip_atomic_load(&bar[lane * 32], __ATOMIC_RELAXED, __HIP_MEMORY_SCOPE_AGENT);
                if (__all(v >= tgt)) break;
                __builtin_amdgcn_s_sleep(1);
            }
        }
        __syncthreads();
        // Compiler barrier: keep the h_all atomic loads of the next iteration
        // from being scheduled above the poll exit. No runtime cost.
        asm volatile("" ::: "memory");

        g0 = n0; g1 = n1; g2 = n2; g3 = n3;
    }
}

// ---------------------------------------------------------------------------
// Fallback: R2-style weight streaming, 256 WGs x 8 waves (proven correct).
// ---------------------------------------------------------------------------
template<typename WT>
__global__ __launch_bounds__(NTHR, 2) void lstm_stream(
    const float* __restrict__ x,
    const WT* __restrict__ Wih1, const WT* __restrict__ Whh1,
    const float* __restrict__ bih1, const float* __restrict__ bhh1,
    const WT* __restrict__ Wih2, const WT* __restrict__ Whh2,
    const float* __restrict__ bih2, const float* __restrict__ bhh2,
    const WT* __restrict__ Wlin, const float* __restrict__ blin,
    float* __restrict__ out,
    int* bar, float* h1buf, float* h2buf)
{
    const int wg   = blockIdx.x;
    const int wave = threadIdx.x >> 6;
    const int lane = threadIdx.x & 63;
    const int unit = wg * 8 + wave;

    const int r0 = unit, r1 = DIM_H + unit, r2 = 2 * DIM_H + unit, r3 = 3 * DIM_H + unit;
    const float b1_0 = bih1[r0] + bhh1[r0];
    const float b1_1 = bih1[r1] + bhh1[r1];
    const float b1_2 = bih1[r2] + bhh1[r2];
    const float b1_3 = bih1[r3] + bhh1[r3];
    const float b2_0 = bih2[r0] + bhh2[r0];
    const float b2_1 = bih2[r1] + bhh2[r1];
    const float b2_2 = bih2[r2] + bhh2[r2];
    const float b2_3 = bih2[r3] + bhh2[r3];

    const WT* wi1_0 = Wih1 + (size_t)r0 * DIM_D;
    const WT* wi1_1 = Wih1 + (size_t)r1 * DIM_D;
    const WT* wi1_2 = Wih1 + (size_t)r2 * DIM_D;
    const WT* wi1_3 = Wih1 + (size_t)r3 * DIM_D;
    const WT* wh1_0 = Whh1 + (size_t)r0 * DIM_H;
    const WT* wh1_1 = Whh1 + (size_t)r1 * DIM_H;
    const WT* wh1_2 = Whh1 + (size_t)r2 * DIM_H;
    const WT* wh1_3 = Whh1 + (size_t)r3 * DIM_H;
    const WT* wi2_0 = Wih2 + (size_t)r0 * DIM_H;
    const WT* wi2_1 = Wih2 + (size_t)r1 * DIM_H;
    const WT* wi2_2 = Wih2 + (size_t)r2 * DIM_H;
    const WT* wi2_3 = Wih2 + (size_t)r3 * DIM_H;
    const WT* wh2_0 = Whh2 + (size_t)r0 * DIM_H;
    const WT* wh2_1 = Whh2 + (size_t)r1 * DIM_H;
    const WT* wh2_2 = Whh2 + (size_t)r2 * DIM_H;
    const WT* wh2_3 = Whh2 + (size_t)r3 * DIM_H;

    const bool  do_y = (wg < DIM_OUT) && (wave == 0);
    const float by   = (wg < DIM_OUT) ? blin[wg] : 0.0f;
    const WT*   wy   = Wlin + (size_t)(wg < DIM_OUT ? wg : 0) * DIM_H;

    float c1 = 0.0f, c2 = 0.0f;

    for (int p = 0; p < T_STEPS + 2; ++p) {
        const float* h1_prev  = h1buf + (size_t)((p + 1) & 1) * DIM_H;
        float*       h1_cur   = h1buf + (size_t)(p & 1) * DIM_H;
        const float* h2_prev2 = h2buf + (size_t)(p & 1) * DIM_H;
        float*       h2_cur   = h2buf + (size_t)((p + 1) & 1) * DIM_H;

        if (p < T_STEPS) {
            float a0 = 0.f, a1 = 0.f, a2 = 0.f, a3 = 0.f;
            dot4<DIM_D>(x + (size_t)p * DIM_D, wi1_0, wi1_1, wi1_2, wi1_3, lane, a0, a1, a2, a3);
            dot4<DIM_H>(h1_prev, wh1_0, wh1_1, wh1_2, wh1_3, lane, a0, a1, a2, a3);
            a0 = wave_reduce(a0); a1 = wave_reduce(a1);
            a2 = wave_reduce(a2); a3 = wave_reduce(a3);
            const float gi = sigf(a0 + b1_0);
            const float gf = sigf(a1 + b1_1);
            const float gg = tanh_f(a2 + b1_2);
            const float go = sigf(a3 + b1_3);
            c1 = fmaf(gf, c1, gi * gg);
            if (lane == 0) h1_cur[unit] = go * tanh_f(c1);
        }

        if (p >= 1 && p <= T_STEPS) {
            float a0 = 0.f, a1 = 0.f, a2 = 0.f, a3 = 0.f;
            dot4<DIM_H>(h1_prev,  wi2_0, wi2_1, wi2_2, wi2_3, lane, a0, a1, a2, a3);
            dot4<DIM_H>(h2_prev2, wh2_0, wh2_1, wh2_2, wh2_3, lane, a0, a1, a2, a3);
            a0 = wave_reduce(a0); a1 = wave_reduce(a1);
            a2 = wave_reduce(a2); a3 = wave_reduce(a3);
            const float gi = sigf(a0 + b2_0);
            const float gf = sigf(a1 + b2_1);
            const float gg = tanh_f(a2 + b2_2);
            const float go = sigf(a3 + b2_3);
            c2 = fmaf(gf, c2, gi * gg);
            if (lane == 0) h2_cur[unit] = go * tanh_f(c2);
        }

        if (do_y && p >= 2) {
            float a = 0.f;
#pragma unroll
            for (int i = 0; i < DIM_H / 512; ++i) {
                const int e = (lane + 64 * i) * 8;
                a = dot8(load8(h2_prev2, e), load8(wy, e), a);
            }
            a = wave_reduce(a);
            if (lane == 0) out[(size_t)(p - 2) * DIM_OUT + wg] = a + by;
        }

        grid_barrier<8>(bar, wg, p);
    }
}

extern "C" void kernel_launch(void* const* d_in, const int* in_sizes, int n_in,
                              void* d_out, int out_size, void* d_ws, size_t ws_size,
                              hipStream_t stream) {
    const float* x    = (const float*)d_in[0];
    const float* Wih1 = (const float*)d_in[1];
    const float* Whh1 = (const float*)d_in[2];
    const float* bih1 = (const float*)d_in[3];
    const float* bhh1 = (const float*)d_in[4];
    const float* Wih2 = (const float*)d_in[5];
    const float* Whh2 = (const float*)d_in[6];
    const float* bih2 = (const float*)d_in[7];
    const float* bhh2 = (const float*)d_in[8];
    const float* Wlin = (const float*)d_in[9];
    const float* blin = (const float*)d_in[10];
    float* out = (float*)d_out;

    int*   barA  = (int*)d_ws;                       // 32 counters, ints [0,1024)
    int*   barB  = barA + 1024;                      // 32 counters, ints [1024,2048)
    float* h1buf = (float*)((char*)d_ws + 8192);     // legacy fallback state
    float* h2buf = h1buf + 2 * DIM_H;

    lstm_init<<<16, 256, 0, stream>>>(barA, h1buf, h2buf);

    // Workspace layout
    size_t off = WS_WEIGHT_OFF;
    __half* hWih1 = (__half*)((char*)d_ws + off); off += sizeof(__half) * (size_t)N_WIH1;
    __half* hWhh1 = (__half*)((char*)d_ws + off); off += sizeof(__half) * (size_t)N_WHH1;
    __half* hWih2 = (__half*)((char*)d_ws + off); off += sizeof(__half) * (size_t)N_WIH2;
    __half* hWhh2 = (__half*)((char*)d_ws + off); off += sizeof(__half) * (size_t)N_WHH2;
    __half* hWlin = (__half*)((char*)d_ws + off); off += sizeof(__half) * (size_t)N_WLIN;
    const size_t need_w = off;
    float* Gbuf   = (float*)((char*)d_ws + off); off += sizeof(float) * (size_t)T_STEPS * DIM_H4;
    float* h1_all = (float*)((char*)d_ws + off); off += sizeof(float) * (size_t)T_STEPS * DIM_H;
    float* h2_all = (float*)((char*)d_ws + off); off += sizeof(float) * (size_t)T_STEPS * DIM_H;
    const size_t need_full = off;

    const bool have_w    = (ws_size >= need_w);
    const bool have_full = (ws_size >= need_full);

    if (have_w) {
        const float* srcs[5] = { Wih1, Whh1, Wih2, Whh2, Wlin };
        __half*      dsts[5] = { hWih1, hWhh1, hWih2, hWhh2, hWlin };
        const int    ns[5]   = { N_WIH1, N_WHH1, N_WIH2, N_WHH2, N_WLIN };
        for (int m = 0; m < 5; ++m) {
            int n4 = ns[m] / 4;
            convert_f16<<<(n4 + 255) / 256, 256, 0, stream>>>(srcs[m], dsts[m], n4);
        }
    }

    // Fallback argument blocks (streaming paths).
    const __half* cWih1 = hWih1; const __half* cWhh1 = hWhh1;
    const __half* cWih2 = hWih2; const __half* cWhh2 = hWhh2;
    const __half* cWlin = hWlin;
    void* argsH[] = {
        (void*)&x,
        (void*)&cWih1, (void*)&cWhh1, (void*)&bih1, (void*)&bhh1,
        (void*)&cWih2, (void*)&cWhh2, (void*)&bih2, (void*)&bhh2,
        (void*)&cWlin, (void*)&blin,
        (void*)&out, (void*)&barA, (void*)&h1buf, (void*)&h2buf
    };
    void* argsF[] = {
        (void*)&x,
        (void*)&Wih1, (void*)&Whh1, (void*)&bih1, (void*)&bhh1,
        (void*)&Wih2, (void*)&Whh2, (void*)&bih2, (void*)&bhh2,
        (void*)&Wlin, (void*)&blin,
        (void*)&out, (void*)&barA, (void*)&h1buf, (void*)&h2buf
    };

    if (have_full) {
        // Phase 1: G = x @ Wih1^T   [T x 4H], K = D
        gemm_xwT<<<dim3(DIM_H4 / GT_N, T_STEPS / GT_M), 256, 0, stream>>>(
            x, hWih1, nullptr, Gbuf, T_STEPS, DIM_H4, DIM_D, 0);

        // Phase 2: sweep A (h1 recurrence, Whh1 in LDS)
        const float* gA = Gbuf; const __half* wA = hWhh1;
        float* hA = h1_all; int* bA = barA;
        void* argsA[] = { (void*)&gA, (void*)&wA, (void*)&bih1, (void*)&bhh1,
                          (void*)&hA, (void*)&bA };
        hipError_t e = hipLaunchCooperativeKernel((const void*)lstm_sweep,
                                                  dim3(256), dim3(NTHR), argsA, 0, stream);
        if (e == hipSuccess) {
            // Phase 3: G = h1_all @ Wih2^T   [T x 4H], K = H
            gemm_xwT<<<dim3(DIM_H4 / GT_N, T_STEPS / GT_M), 256, 0, stream>>>(
                h1_all, hWih2, nullptr, Gbuf, T_STEPS, DIM_H4, DIM_H, 0);

            // Phase 4: sweep B (h2 recurrence, Whh2 in LDS)
            const float* gB = Gbuf; const __half* wB = hWhh2;
            float* hB = h2_all; int* bB = barB;
            void* argsB[] = { (void*)&gB, (void*)&wB, (void*)&bih2, (void*)&bhh2,
                              (void*)&hB, (void*)&bB };
            hipLaunchCooperativeKernel((const void*)lstm_sweep,
                                       dim3(256), dim3(NTHR), argsB, 0, stream);

            // Phase 5: out = h2_all @ Wlin^T + blin   [T x OUT], K = H
            gemm_xwT<<<dim3(DIM_OUT / GT_N, T_STEPS / GT_M), 256, 0, stream>>>(
                h2_all, hWlin, blin, out, T_STEPS, DIM_OUT, DIM_H, 1);
        } else {
            // Cooperative validation failed: proven fp16 streaming fallback.
            hipLaunchCooperativeKernel((const void*)lstm_stream<__half>,
                                       dim3(256), dim3(NTHR), argsH, 0, stream);
        }
    } else if (have_w) {
        hipLaunchCooperativeKernel((const void*)lstm_stream<__half>,
                                   dim3(256), dim3(NTHR), argsH, 0, stream);
    } else {
        hipLaunchCooperativeKernel((const void*)lstm_stream<float>,
                                   dim3(256), dim3(NTHR), argsF, 0, stream);
    }
}

// Round 11
// 30778.088 us; speedup vs baseline: 1.7373x; 1.1603x over previous
//
#include <hip/hip_runtime.h>
#include <hip/hip_fp16.h>

// LSTM_54537494725306: 2-layer LSTM, T=2048, D=512, H=2048, OUT=64, fp32 in/out.
// R13 = R12 temporal-split + flat barrier, fixing the two real per-step costs
// R12's counters exposed:
//   1. Arrival RMW was ACQ_REL -> acquire half invalidates L1/L2 every step
//      (FETCH stayed 160KB/step: G/h refetched each iteration). Now RELEASE
//      only (result never read; release = vmcnt drain, no cache maintenance).
//   2. Every wave atomic-loaded the FULL 8KB h row (16 MB/step uncached
//      coherent traffic). Now the WG loads h[t] ONCE into an 8KB LDS buffer
//      (512 thr x 4 floats, atomic relaxed) after poll-detect; all 8 waves
//      consume from LDS. 8x less coherent traffic (2 MB/step).
// Consumer ordering (validated in R12): producer h atomic-store -> syncthreads
// (vmcnt drain) -> RELEASE RMW on group counter; consumer relaxed-polls the 32
// counters, compiler barrier, then relaxed atomic h loads read the coherence
// point which already holds the released values. No acquire fence anywhere.
// Phases: GEMM1 (x@Wih1^T) -> sweepA (Whh1 in 128KiB LDS/CU) -> GEMM2
// (h1@Wih2^T) -> sweepB (Whh2 in LDS) -> GEMMY (h2@Wlin^T + b).
// Math identical to R9-R12 (fp16 weights -> f32 cvt -> f32 fmaf chains).

#define T_STEPS 2048
#define DIM_D   512
#define DIM_H   2048
#define DIM_H4  8192
#define DIM_OUT 64
#define NTHR    512

#define N_WIH1 (4 * DIM_H * DIM_D)   //  4,194,304
#define N_WHH1 (4 * DIM_H * DIM_H)   // 16,777,216
#define N_WIH2 (4 * DIM_H * DIM_H)
#define N_WHH2 (4 * DIM_H * DIM_H)
#define N_WLIN (DIM_OUT * DIM_H)     //    131,072
#define WS_WEIGHT_OFF 65536

__device__ __forceinline__ float sigf(float x)   { return 1.0f / (1.0f + __expf(-x)); }
__device__ __forceinline__ float tanh_f(float x) { return 1.0f - 2.0f / (__expf(2.0f * x) + 1.0f); }

__device__ __forceinline__ float wave_reduce(float v) {
#pragma unroll
    for (int off = 32; off > 0; off >>= 1) v += __shfl_xor(v, off, 64);
    return v;
}

struct F8 { float4 a, b; };

__device__ __forceinline__ F8 load8(const float* __restrict__ p, int e) {
    F8 r;
    const float4* q = (const float4*)(p + e);
    r.a = q[0]; r.b = q[1];
    return r;
}

__device__ __forceinline__ F8 cvt8(uint4 u) {
    float2 f0 = __half22float2(*(__half2*)&u.x);
    float2 f1 = __half22float2(*(__half2*)&u.y);
    float2 f2 = __half22float2(*(__half2*)&u.z);
    float2 f3 = __half22float2(*(__half2*)&u.w);
    F8 r;
    r.a = make_float4(f0.x, f0.y, f1.x, f1.y);
    r.b = make_float4(f2.x, f2.y, f3.x, f3.y);
    return r;
}

__device__ __forceinline__ F8 load8(const __half* __restrict__ p, int e) {
    uint4 u = *(const uint4*)(p + e);
    return cvt8(u);
}

__device__ __forceinline__ float dot8(const F8& v, const F8& w, float acc) {
    acc = fmaf(v.a.x, w.a.x, acc); acc = fmaf(v.a.y, w.a.y, acc);
    acc = fmaf(v.a.z, w.a.z, acc); acc = fmaf(v.a.w, w.a.w, acc);
    acc = fmaf(v.b.x, w.b.x, acc); acc = fmaf(v.b.y, w.b.y, acc);
    acc = fmaf(v.b.z, w.b.z, acc); acc = fmaf(v.b.w, w.b.w, acc);
    return acc;
}

// 4-row dot over K elements (streaming fallback path only).
template<int K, typename WT>
__device__ __forceinline__ void dot4(const float* __restrict__ v,
                                     const WT* __restrict__ w0, const WT* __restrict__ w1,
                                     const WT* __restrict__ w2, const WT* __restrict__ w3,
                                     int lane, float& a0, float& a1, float& a2, float& a3) {
#pragma unroll
    for (int i = 0; i < K / 512; ++i) {
        const int e = (lane + 64 * i) * 8;
        const F8 vv = load8(v, e);
        a0 = dot8(vv, load8(w0, e), a0);
        a1 = dot8(vv, load8(w1, e), a1);
        a2 = dot8(vv, load8(w2, e), a2);
        a3 = dot8(vv, load8(w3, e), a3);
    }
}

// Two-level sense-free barrier over NGRP*32 workgroups (fallback kernels only).
template<int NGRP>
__device__ __forceinline__ void grid_barrier(int* bar, int wg, int g) {
    __syncthreads();
    if (threadIdx.x == 0) {
        const int grp = wg >> 5;
        int a = __hip_atomic_fetch_add(&bar[grp * 32], 1, __ATOMIC_ACQ_REL, __HIP_MEMORY_SCOPE_AGENT);
        if (a == 31) {
            int r = __hip_atomic_fetch_add(&bar[NGRP * 32], 1, __ATOMIC_ACQ_REL, __HIP_MEMORY_SCOPE_AGENT);
            if (r == NGRP - 1) {
#pragma unroll
                for (int i = 0; i < NGRP; ++i)
                    __hip_atomic_store(&bar[i * 32], 0, __ATOMIC_RELAXED, __HIP_MEMORY_SCOPE_AGENT);
                __hip_atomic_store(&bar[NGRP * 32], 0, __ATOMIC_RELAXED, __HIP_MEMORY_SCOPE_AGENT);
                __hip_atomic_store(&bar[NGRP * 32 + 32], g + 1, __ATOMIC_RELEASE, __HIP_MEMORY_SCOPE_AGENT);
            }
        }
        while (__hip_atomic_load(&bar[NGRP * 32 + 32], __ATOMIC_RELAXED, __HIP_MEMORY_SCOPE_AGENT) <= g) {
            __builtin_amdgcn_s_sleep(2);
        }
        __builtin_amdgcn_fence(__ATOMIC_ACQUIRE, "agent");
    }
    __syncthreads();
}

__global__ void lstm_init(int* bar, float* h1buf, float* h2buf) {
    int i = threadIdx.x + blockIdx.x * blockDim.x;
    if (i < 2048) bar[i] = 0;               // barA [0,1024) + barB [1024,2048)
    if (i < 2 * DIM_H) { h1buf[i] = 0.0f; h2buf[i] = 0.0f; }
}

// fp32 -> fp16 (RNE), 4 elements/thread.
__global__ void convert_f16(const float* __restrict__ src, __half* __restrict__ dst, int n4) {
    int i = threadIdx.x + blockIdx.x * blockDim.x;
    if (i < n4) {
        float4 f = ((const float4*)src)[i];
        __half2 h01 = __floats2half2_rn(f.x, f.y);
        __half2 h23 = __floats2half2_rn(f.z, f.w);
        uint2 o;
        o.x = *(unsigned int*)&h01;
        o.y = *(unsigned int*)&h23;
        ((uint2*)dst)[i] = o;
    }
}

// ---------------------------------------------------------------------------
// GEMM: C[M][N] = A[M][K](fp32) * B[N][K](fp16)^T  (+ bias[n] if hasBias).
// 64x64 tile, 256 threads, 4x4 micro-tile/thread, K-chunks of 32.
// ---------------------------------------------------------------------------
#define GT_M 64
#define GT_N 64
#define GT_K 32

__global__ __launch_bounds__(256) void gemm_xwT(
    const float* __restrict__ A, const __half* __restrict__ B,
    const float* __restrict__ bias, float* __restrict__ C,
    int M, int N, int K, int hasBias)
{
    __shared__ float  As[GT_K][GT_M + 4];   // [32][68] fp32, 8.5 KB
    __shared__ ushort Bs[GT_K][GT_N + 8];   // [32][72] fp16 bits, 4.5 KB

    const int t  = threadIdx.x;
    const int tx = t & 15, ty = t >> 4;
    const int n0 = blockIdx.x * GT_N;
    const int m0 = blockIdx.y * GT_M;

    float acc[4][4];
#pragma unroll
    for (int i = 0; i < 4; ++i)
#pragma unroll
        for (int j = 0; j < 4; ++j) acc[i][j] = 0.f;

    for (int kc = 0; kc < K; kc += GT_K) {
#pragma unroll
        for (int s = 0; s < 2; ++s) {
            const int i  = t + s * 256;
            const int r  = i >> 3;
            const int c4 = (i & 7) * 4;
            const float4 av = *(const float4*)(A + (size_t)(m0 + r) * K + kc + c4);
            As[c4 + 0][r] = av.x; As[c4 + 1][r] = av.y;
            As[c4 + 2][r] = av.z; As[c4 + 3][r] = av.w;
            const uint2 bv = *(const uint2*)(B + (size_t)(n0 + r) * K + kc + c4);
            Bs[c4 + 0][r] = (ushort)(bv.x & 0xffffu);
            Bs[c4 + 1][r] = (ushort)(bv.x >> 16);
            Bs[c4 + 2][r] = (ushort)(bv.y & 0xffffu);
            Bs[c4 + 3][r] = (ushort)(bv.y >> 16);
        }
        __syncthreads();
#pragma unroll
        for (int kk = 0; kk < GT_K; ++kk) {
            const float4 a4 = *(const float4*)&As[kk][ty * 4];
            const uint2  bu = *(const uint2*)&Bs[kk][tx * 4];
            const float2 b01 = __half22float2(*(const __half2*)&bu.x);
            const float2 b23 = __half22float2(*(const __half2*)&bu.y);
            const float a0 = a4.x, a1 = a4.y, a2 = a4.z, a3 = a4.w;
            const float b0 = b01.x, b1 = b01.y, b2 = b23.x, b3 = b23.y;
            acc[0][0] = fmaf(a0, b0, acc[0][0]); acc[0][1] = fmaf(a0, b1, acc[0][1]);
            acc[0][2] = fmaf(a0, b2, acc[0][2]); acc[0][3] = fmaf(a0, b3, acc[0][3]);
            acc[1][0] = fmaf(a1, b0, acc[1][0]); acc[1][1] = fmaf(a1, b1, acc[1][1]);
            acc[1][2] = fmaf(a1, b2, acc[1][2]); acc[1][3] = fmaf(a1, b3, acc[1][3]);
            acc[2][0] = fmaf(a2, b0, acc[2][0]); acc[2][1] = fmaf(a2, b1, acc[2][1]);
            acc[2][2] = fmaf(a2, b2, acc[2][2]); acc[2][3] = fmaf(a2, b3, acc[2][3]);
            acc[3][0] = fmaf(a3, b0, acc[3][0]); acc[3][1] = fmaf(a3, b1, acc[3][1]);
            acc[3][2] = fmaf(a3, b2, acc[3][2]); acc[3][3] = fmaf(a3, b3, acc[3][3]);
        }
        __syncthreads();
    }

    float4 bv = make_float4(0.f, 0.f, 0.f, 0.f);
    if (hasBias) {
        const int n = n0 + tx * 4;
        bv = make_float4(bias[n], bias[n + 1], bias[n + 2], bias[n + 3]);
    }
#pragma unroll
    for (int i = 0; i < 4; ++i) {
        const int m = m0 + ty * 4 + i;
        float4 v = make_float4(acc[i][0] + bv.x, acc[i][1] + bv.y,
                               acc[i][2] + bv.z, acc[i][3] + bv.w);
        *(float4*)(C + (size_t)m * N + n0 + tx * 4) = v;
    }
}

// ---------------------------------------------------------------------------
// Sequential sweep, flat one-hop barrier, fence-free, LDS-shared h row.
// 256 WGs x 512 thr (8 waves), 1 wave/unit; Whh rows in 128 KiB LDS/CU +
// 8 KB LDS h-row buffer. Arrival RMW is RELEASE-only (no invalidate).
// After poll-detect, the WG loads h[t] once (atomic relaxed, coherence point)
// into hlds; all waves consume from LDS next step.
// ---------------------------------------------------------------------------
__global__ __launch_bounds__(NTHR, 2) void lstm_sweep(
    const float* __restrict__ G,     // [T][4H] x-part pre-activations
    const __half* __restrict__ Whh,  // [4H][H] fp16
    const float* __restrict__ bi, const float* __restrict__ bh,
    float* __restrict__ h_all,       // [T][H]
    int* bar)                        // 32 monotonic counters at bar[g*32]
{
    const int wg   = blockIdx.x;
    const int wave = threadIdx.x >> 6;
    const int lane = threadIdx.x & 63;
    const int unit = wg * 8 + wave;
    const int grp  = wg >> 3;        // 32 groups of 8 WGs

    __shared__ uint4 ldsW[8][4][DIM_H / 8];   // 131072 B
    __shared__ float hlds[DIM_H];             //   8192 B

#pragma unroll
    for (int g = 0; g < 4; ++g) {
        const uint4* q = (const uint4*)(Whh + (size_t)(g * DIM_H + unit) * DIM_H);
#pragma unroll
        for (int j = 0; j < 4; ++j)
            ldsW[wave][g][lane + 64 * j] = q[lane + 64 * j];
    }
    const float b0 = bi[0 * DIM_H + unit] + bh[0 * DIM_H + unit];
    const float b1 = bi[1 * DIM_H + unit] + bh[1 * DIM_H + unit];
    const float b2 = bi[2 * DIM_H + unit] + bh[2 * DIM_H + unit];
    const float b3 = bi[3 * DIM_H + unit] + bh[3 * DIM_H + unit];
    __syncthreads();

    float c = 0.0f;

    // G[0] preloaded (same-address across lanes -> broadcast).
    float g0 = G[0 * DIM_H + unit];
    float g1 = G[1 * DIM_H + unit];
    float g2 = G[2 * DIM_H + unit];
    float g3 = G[3 * DIM_H + unit];

    for (int t = 0; t < T_STEPS; ++t) {
        float a0 = 0.f, a1 = 0.f, a2 = 0.f, a3 = 0.f;
        if (t > 0) {
#pragma unroll
            for (int j = 0; j < 4; ++j) {
                const float4* hp4 = (const float4*)&hlds[(lane + 64 * j) * 8];
                F8 hv; hv.a = hp4[0]; hv.b = hp4[1];
                a0 = dot8(hv, cvt8(ldsW[wave][0][lane + 64 * j]), a0);
                a1 = dot8(hv, cvt8(ldsW[wave][1][lane + 64 * j]), a1);
                a2 = dot8(hv, cvt8(ldsW[wave][2][lane + 64 * j]), a2);
                a3 = dot8(hv, cvt8(ldsW[wave][3][lane + 64 * j]), a3);
            }
            a0 = wave_reduce(a0); a1 = wave_reduce(a1);
            a2 = wave_reduce(a2); a3 = wave_reduce(a3);
        }

        const float gi = sigf  (a0 + g0 + b0);
        const float gf = sigf  (a1 + g1 + b1);
        const float gg = tanh_f(a2 + g2 + b2);
        const float go = sigf  (a3 + g3 + b3);
        c = fmaf(gf, c, gi * gg);
        const float hv = go * tanh_f(c);
        if (lane == 0)
            __hip_atomic_store(&h_all[(size_t)t * DIM_H + unit], hv,
                               __ATOMIC_RELAXED, __HIP_MEMORY_SCOPE_AGENT);

        if (t + 1 >= T_STEPS) break;   // kernel boundary syncs the final step

        // ---- arrive: RELEASE-only RMW (vmcnt drain via syncthreads; no
        //      cache invalidate). Orders the h store before the counter bump.
        __syncthreads();
        if (threadIdx.x == 0)
            __hip_atomic_fetch_add(&bar[grp * 32], 1, __ATOMIC_RELEASE, __HIP_MEMORY_SCOPE_AGENT);

        // ---- prefetch next-step G while the grid converges (cacheable) ----
        const size_t nb = (size_t)(t + 1) * DIM_H4;
        const float n0 = G[nb + 0 * DIM_H + unit];
        const float n1 = G[nb + 1 * DIM_H + unit];
        const float n2 = G[nb + 2 * DIM_H + unit];
        const float n3 = G[nb + 3 * DIM_H + unit];

        // ---- wait: lane i polls group counter i; all must reach 8*(t+1) ----
        if (wave == 0) {
            const int tgt = 8 * (t + 1);
            for (;;) {
                int v = tgt;
                if (lane < 32)
                    v = __hip_atomic_load(&bar[lane * 32], __ATOMIC_RELAXED, __HIP_MEMORY_SCOPE_AGENT);
                if (__all(v >= tgt)) break;
                __builtin_amdgcn_s_sleep(1);
            }
        }
        __syncthreads();
        asm volatile("" ::: "memory");   // pin h loads below the poll exit

        // ---- load h[t] ONCE into LDS (coherence-point reads, 4 floats/thr) ----
        {
            const unsigned long long* hq =
                (const unsigned long long*)(h_all + (size_t)t * DIM_H);
            const int i2 = threadIdx.x * 2;
            unsigned long long u0 = __hip_atomic_load(hq + i2,     __ATOMIC_RELAXED, __HIP_MEMORY_SCOPE_AGENT);
            unsigned long long u1 = __hip_atomic_load(hq + i2 + 1, __ATOMIC_RELAXED, __HIP_MEMORY_SCOPE_AGENT);
            const float2 f0 = *(float2*)&u0;
            const float2 f1 = *(float2*)&u1;
            *(float4*)&hlds[threadIdx.x * 4] = make_float4(f0.x, f0.y, f1.x, f1.y);
        }
        __syncthreads();

        g0 = n0; g1 = n1; g2 = n2; g3 = n3;
    }
}

// ---------------------------------------------------------------------------
// Fallback: R2-style weight streaming, 256 WGs x 8 waves (proven correct).
// ---------------------------------------------------------------------------
template<typename WT>
__global__ __launch_bounds__(NTHR, 2) void lstm_stream(
    const float* __restrict__ x,
    const WT* __restrict__ Wih1, const WT* __restrict__ Whh1,
    const float* __restrict__ bih1, const float* __restrict__ bhh1,
    const WT* __restrict__ Wih2, const WT* __restrict__ Whh2,
    const float* __restrict__ bih2, const float* __restrict__ bhh2,
    const WT* __restrict__ Wlin, const float* __restrict__ blin,
    float* __restrict__ out,
    int* bar, float* h1buf, float* h2buf)
{
    const int wg   = blockIdx.x;
    const int wave = threadIdx.x >> 6;
    const int lane = threadIdx.x & 63;
    const int unit = wg * 8 + wave;

    const int r0 = unit, r1 = DIM_H + unit, r2 = 2 * DIM_H + unit, r3 = 3 * DIM_H + unit;
    const float b1_0 = bih1[r0] + bhh1[r0];
    const float b1_1 = bih1[r1] + bhh1[r1];
    const float b1_2 = bih1[r2] + bhh1[r2];
    const float b1_3 = bih1[r3] + bhh1[r3];
    const float b2_0 = bih2[r0] + bhh2[r0];
    const float b2_1 = bih2[r1] + bhh2[r1];
    const float b2_2 = bih2[r2] + bhh2[r2];
    const float b2_3 = bih2[r3] + bhh2[r3];

    const WT* wi1_0 = Wih1 + (size_t)r0 * DIM_D;
    const WT* wi1_1 = Wih1 + (size_t)r1 * DIM_D;
    const WT* wi1_2 = Wih1 + (size_t)r2 * DIM_D;
    const WT* wi1_3 = Wih1 + (size_t)r3 * DIM_D;
    const WT* wh1_0 = Whh1 + (size_t)r0 * DIM_H;
    const WT* wh1_1 = Whh1 + (size_t)r1 * DIM_H;
    const WT* wh1_2 = Whh1 + (size_t)r2 * DIM_H;
    const WT* wh1_3 = Whh1 + (size_t)r3 * DIM_H;
    const WT* wi2_0 = Wih2 + (size_t)r0 * DIM_H;
    const WT* wi2_1 = Wih2 + (size_t)r1 * DIM_H;
    const WT* wi2_2 = Wih2 + (size_t)r2 * DIM_H;
    const WT* wi2_3 = Wih2 + (size_t)r3 * DIM_H;
    const WT* wh2_0 = Whh2 + (size_t)r0 * DIM_H;
    const WT* wh2_1 = Whh2 + (size_t)r1 * DIM_H;
    const WT* wh2_2 = Whh2 + (size_t)r2 * DIM_H;
    const WT* wh2_3 = Whh2 + (size_t)r3 * DIM_H;

    const bool  do_y = (wg < DIM_OUT) && (wave == 0);
    const float by   = (wg < DIM_OUT) ? blin[wg] : 0.0f;
    const WT*   wy   = Wlin + (size_t)(wg < DIM_OUT ? wg : 0) * DIM_H;

    float c1 = 0.0f, c2 = 0.0f;

    for (int p = 0; p < T_STEPS + 2; ++p) {
        const float* h1_prev  = h1buf + (size_t)((p + 1) & 1) * DIM_H;
        float*       h1_cur   = h1buf + (size_t)(p & 1) * DIM_H;
        const float* h2_prev2 = h2buf + (size_t)(p & 1) * DIM_H;
        float*       h2_cur   = h2buf + (size_t)((p + 1) & 1) * DIM_H;

        if (p < T_STEPS) {
            float a0 = 0.f, a1 = 0.f, a2 = 0.f, a3 = 0.f;
            dot4<DIM_D>(x + (size_t)p * DIM_D, wi1_0, wi1_1, wi1_2, wi1_3, lane, a0, a1, a2, a3);
            dot4<DIM_H>(h1_prev, wh1_0, wh1_1, wh1_2, wh1_3, lane, a0, a1, a2, a3);
            a0 = wave_reduce(a0); a1 = wave_reduce(a1);
            a2 = wave_reduce(a2); a3 = wave_reduce(a3);
            const float gi = sigf(a0 + b1_0);
            const float gf = sigf(a1 + b1_1);
            const float gg = tanh_f(a2 + b1_2);
            const float go = sigf(a3 + b1_3);
            c1 = fmaf(gf, c1, gi * gg);
            if (lane == 0) h1_cur[unit] = go * tanh_f(c1);
        }

        if (p >= 1 && p <= T_STEPS) {
            float a0 = 0.f, a1 = 0.f, a2 = 0.f, a3 = 0.f;
            dot4<DIM_H>(h1_prev,  wi2_0, wi2_1, wi2_2, wi2_3, lane, a0, a1, a2, a3);
            dot4<DIM_H>(h2_prev2, wh2_0, wh2_1, wh2_2, wh2_3, lane, a0, a1, a2, a3);
            a0 = wave_reduce(a0); a1 = wave_reduce(a1);
            a2 = wave_reduce(a2); a3 = wave_reduce(a3);
            const float gi = sigf(a0 + b2_0);
            const float gf = sigf(a1 + b2_1);
            const float gg = tanh_f(a2 + b2_2);
            const float go = sigf(a3 + b2_3);
            c2 = fmaf(gf, c2, gi * gg);
            if (lane == 0) h2_cur[unit] = go * tanh_f(c2);
        }

        if (do_y && p >= 2) {
            float a = 0.f;
#pragma unroll
            for (int i = 0; i < DIM_H / 512; ++i) {
                const int e = (lane + 64 * i) * 8;
                a = dot8(load8(h2_prev2, e), load8(wy, e), a);
            }
            a = wave_reduce(a);
            if (lane == 0) out[(size_t)(p - 2) * DIM_OUT + wg] = a + by;
        }

        grid_barrier<8>(bar, wg, p);
    }
}

extern "C" void kernel_launch(void* const* d_in, const int* in_sizes, int n_in,
                              void* d_out, int out_size, void* d_ws, size_t ws_size,
                              hipStream_t stream) {
    const float* x    = (const float*)d_in[0];
    const float* Wih1 = (const float*)d_in[1];
    const float* Whh1 = (const float*)d_in[2];
    const float* bih1 = (const float*)d_in[3];
    const float* bhh1 = (const float*)d_in[4];
    const float* Wih2 = (const float*)d_in[5];
    const float* Whh2 = (const float*)d_in[6];
    const float* bih2 = (const float*)d_in[7];
    const float* bhh2 = (const float*)d_in[8];
    const float* Wlin = (const float*)d_in[9];
    const float* blin = (const float*)d_in[10];
    float* out = (float*)d_out;

    int*   barA  = (int*)d_ws;                       // 32 counters, ints [0,1024)
    int*   barB  = barA + 1024;                      // 32 counters, ints [1024,2048)
    float* h1buf = (float*)((char*)d_ws + 8192);     // legacy fallback state
    float* h2buf = h1buf + 2 * DIM_H;

    lstm_init<<<16, 256, 0, stream>>>(barA, h1buf, h2buf);

    // Workspace layout
    size_t off = WS_WEIGHT_OFF;
    __half* hWih1 = (__half*)((char*)d_ws + off); off += sizeof(__half) * (size_t)N_WIH1;
    __half* hWhh1 = (__half*)((char*)d_ws + off); off += sizeof(__half) * (size_t)N_WHH1;
    __half* hWih2 = (__half*)((char*)d_ws + off); off += sizeof(__half) * (size_t)N_WIH2;
    __half* hWhh2 = (__half*)((char*)d_ws + off); off += sizeof(__half) * (size_t)N_WHH2;
    __half* hWlin = (__half*)((char*)d_ws + off); off += sizeof(__half) * (size_t)N_WLIN;
    const size_t need_w = off;
    float* Gbuf   = (float*)((char*)d_ws + off); off += sizeof(float) * (size_t)T_STEPS * DIM_H4;
    float* h1_all = (float*)((char*)d_ws + off); off += sizeof(float) * (size_t)T_STEPS * DIM_H;
    float* h2_all = (float*)((char*)d_ws + off); off += sizeof(float) * (size_t)T_STEPS * DIM_H;
    const size_t need_full = off;

    const bool have_w    = (ws_size >= need_w);
    const bool have_full = (ws_size >= need_full);

    if (have_w) {
        const float* srcs[5] = { Wih1, Whh1, Wih2, Whh2, Wlin };
        __half*      dsts[5] = { hWih1, hWhh1, hWih2, hWhh2, hWlin };
        const int    ns[5]   = { N_WIH1, N_WHH1, N_WIH2, N_WHH2, N_WLIN };
        for (int m = 0; m < 5; ++m) {
            int n4 = ns[m] / 4;
            convert_f16<<<(n4 + 255) / 256, 256, 0, stream>>>(srcs[m], dsts[m], n4);
        }
    }

    // Fallback argument blocks (streaming paths).
    const __half* cWih1 = hWih1; const __half* cWhh1 = hWhh1;
    const __half* cWih2 = hWih2; const __half* cWhh2 = hWhh2;
    const __half* cWlin = hWlin;
    void* argsH[] = {
        (void*)&x,
        (void*)&cWih1, (void*)&cWhh1, (void*)&bih1, (void*)&bhh1,
        (void*)&cWih2, (void*)&cWhh2, (void*)&bih2, (void*)&bhh2,
        (void*)&cWlin, (void*)&blin,
        (void*)&out, (void*)&barA, (void*)&h1buf, (void*)&h2buf
    };
    void* argsF[] = {
        (void*)&x,
        (void*)&Wih1, (void*)&Whh1, (void*)&bih1, (void*)&bhh1,
        (void*)&Wih2, (void*)&Whh2, (void*)&bih2, (void*)&bhh2,
        (void*)&Wlin, (void*)&blin,
        (void*)&out, (void*)&barA, (void*)&h1buf, (void*)&h2buf
    };

    if (have_full) {
        // Phase 1: G = x @ Wih1^T   [T x 4H], K = D
        gemm_xwT<<<dim3(DIM_H4 / GT_N, T_STEPS / GT_M), 256, 0, stream>>>(
            x, hWih1, nullptr, Gbuf, T_STEPS, DIM_H4, DIM_D, 0);

        // Phase 2: sweep A (h1 recurrence, Whh1 in LDS)
        const float* gA = Gbuf; const __half* wA = hWhh1;
        float* hA = h1_all; int* bA = barA;
        void* argsA[] = { (void*)&gA, (void*)&wA, (void*)&bih1, (void*)&bhh1,
                          (void*)&hA, (void*)&bA };
        hipError_t e = hipLaunchCooperativeKernel((const void*)lstm_sweep,
                                                  dim3(256), dim3(NTHR), argsA, 0, stream);
        if (e == hipSuccess) {
            // Phase 3: G = h1_all @ Wih2^T   [T x 4H], K = H
            gemm_xwT<<<dim3(DIM_H4 / GT_N, T_STEPS / GT_M), 256, 0, stream>>>(
                h1_all, hWih2, nullptr, Gbuf, T_STEPS, DIM_H4, DIM_H, 0);

            // Phase 4: sweep B (h2 recurrence, Whh2 in LDS)
            const float* gB = Gbuf; const __half* wB = hWhh2;
            float* hB = h2_all; int* bB = barB;
            void* argsB[] = { (void*)&gB, (void*)&wB, (void*)&bih2, (void*)&bhh2,
                              (void*)&hB, (void*)&bB };
            hipLaunchCooperativeKernel((const void*)lstm_sweep,
                                       dim3(256), dim3(NTHR), argsB, 0, stream);

            // Phase 5: out = h2_all @ Wlin^T + blin   [T x OUT], K = H
            gemm_xwT<<<dim3(DIM_OUT / GT_N, T_STEPS / GT_M), 256, 0, stream>>>(
                h2_all, hWlin, blin, out, T_STEPS, DIM_OUT, DIM_H, 1);
        } else {
            // Cooperative validation failed: proven fp16 streaming fallback.
            hipLaunchCooperativeKernel((const void*)lstm_stream<__half>,
                                       dim3(256), dim3(NTHR), argsH, 0, stream);
        }
    } else if (have_w) {
        hipLaunchCooperativeKernel((const void*)lstm_stream<__half>,
                                   dim3(256), dim3(NTHR), argsH, 0, stream);
    } else {
        hipLaunchCooperativeKernel((const void*)lstm_stream<float>,
                                   dim3(256), dim3(NTHR), argsF, 0, stream);
    }
}